// Round 11
// baseline (908.579 us; speedup 1.0000x reference)
//
#include <hip/hip_runtime.h>
#include <hip/hip_bf16.h>
#include <math.h>

#define B_ 16
#define N_ 500
#define T_ 12
#define K_ 10
#define NROWS (B_*N_)   // 8000
#define TROWS 6         // rows per work chunk
#define NTCN2 2688      // fixed grid for k_tcn2 (>= max compact chunks 2686)

// ---------------- threefry / gumbel (jax.random.key(42)) ----------------
__device__ __forceinline__ unsigned rotl32(unsigned v, int r){ return (v<<r)|(v>>(32-r)); }

__device__ __forceinline__ void threefry2x32(unsigned k0, unsigned k1,
                                             unsigned c0, unsigned c1,
                                             unsigned &o0, unsigned &o1){
  unsigned ks2 = k0 ^ k1 ^ 0x1BD11BDAu;
  unsigned x0 = c0 + k0, x1 = c1 + k1;
#define TF_R(r) { x0 += x1; x1 = rotl32(x1,(r)); x1 ^= x0; }
  TF_R(13) TF_R(15) TF_R(26) TF_R(6)
  x0 += k1;  x1 += ks2 + 1u;
  TF_R(17) TF_R(29) TF_R(16) TF_R(24)
  x0 += ks2; x1 += k0 + 2u;
  TF_R(13) TF_R(15) TF_R(26) TF_R(6)
  x0 += k0;  x1 += k1 + 3u;
  TF_R(17) TF_R(29) TF_R(16) TF_R(24)
  x0 += k1;  x1 += ks2 + 4u;
  TF_R(13) TF_R(15) TF_R(26) TF_R(6)
  x0 += ks2; x1 += k0 + 5u;
#undef TF_R
  o0 = x0; o1 = x1;
}

// Partitionable threefry (JAX >= 0.4.30): bits[i] = x0 ^ x1 of threefry(key,(0,i)).
// VERIFIED bit-exact vs harness (round 5 pass).
__device__ __forceinline__ float gumbel_at(unsigned idx){
  unsigned b0, b1;
  threefry2x32(0u, 42u, 0u, idx, b0, b1);
  unsigned bits = b0 ^ b1;
  float u = __uint_as_float((bits >> 9) | 0x3f800000u) - 1.0f;  // [0,1)
  u = fmaxf(u, 1.17549435e-38f);
  return -logf(-logf(u));
}

// ---------------- matq = nodes_cb @ w_q ----------------
__global__ __launch_bounds__(256) void k_matq(const float* __restrict__ nodes_cb,
                                              const float* __restrict__ w_q,
                                              float* __restrict__ matq){
  int idx = blockIdx.x*256 + threadIdx.x;
  if (idx >= N_*64) return;
  int n = idx >> 6, d = idx & 63;
  float a = 0.f;
  for (int c = 0; c < 64; ++c) a += nodes_cb[n*64+c] * w_q[c*64+d];
  matq[idx] = a;
}

// ---------------- routing ----------------
// Also emits compact chunk prefix sums at off+16: chunkOff[s] for slot s in
// [0,20], chunkOff[20] = nwork (sum of ceil(cnt*16/TROWS) over 20 slots).
__global__ __launch_bounds__(256) void k_route(const float* __restrict__ env_cb,
                                               const float* __restrict__ w_v,
                                               const float* __restrict__ w_k,
                                               const float* __restrict__ matq,
                                               int* __restrict__ node_list,
                                               int* __restrict__ off){
  __shared__ float smk[K_*64];
  __shared__ float smv[K_*K_];
  __shared__ int sroute[N_];
  int tid = threadIdx.x;
  for (int idx = tid; idx < K_*64; idx += 256){
    int kk = idx >> 6, d = idx & 63;
    float a = 0.f;
    for (int c = 0; c < 64; ++c) a += env_cb[kk*64+c] * w_k[c*64+d];
    smk[idx] = a;
  }
  for (int idx = tid; idx < K_*K_; idx += 256){
    int kk = idx / K_, j = idx % K_;
    float a = 0.f;
    for (int c = 0; c < 64; ++c) a += env_cb[kk*64+c] * w_v[c*K_+j];
    smv[idx] = a;
  }
  __syncthreads();
  for (int n = tid; n < N_; n += 256){
    float s[K_];
    float mx = -1e30f;
    for (int j = 0; j < K_; ++j){
      float a = 0.f;
      for (int d = 0; d < 64; ++d) a += matq[n*64+d]*smk[j*64+d];
      s[j] = a * 0.125f;
      mx = fmaxf(mx, s[j]);
    }
    float sum = 0.f;
    for (int j = 0; j < K_; ++j){ s[j] = expf(s[j]-mx); sum += s[j]; }
    float inv = 1.f/sum;
    int best = 0; float bestv = -1e30f;
    for (int j2 = 0; j2 < K_; ++j2){
      float lg = 0.f;
      for (int j = 0; j < K_; ++j) lg += s[j]*inv*smv[j*K_+j2];
      float tot = lg + gumbel_at((unsigned)(n*K_+j2));
      if (tot > bestv){ bestv = tot; best = j2; }
    }
    sroute[n] = best;
  }
  __syncthreads();
  if (tid == 0){
    int cnt[K_]; for (int j=0;j<K_;++j) cnt[j]=0;
    for (int n=0;n<N_;++n) cnt[sroute[n]]++;
    int acc=0;
    for (int j=0;j<K_;++j){ off[j]=acc; acc+=cnt[j]; }
    off[K_]=acc;
    int pos[K_]; for (int j=0;j<K_;++j) pos[j]=off[j];
    for (int n=0;n<N_;++n) node_list[pos[sroute[n]]++] = n;
    // compact work-chunk prefix sums (slot-major, both paths of expert k adjacent)
    int* chunkOff = off + 16;
    int ck = 0;
    chunkOff[0] = 0;
    for (int s = 0; s < 2*K_; ++s){
      int rows = cnt[s >> 1] * 16;
      ck += (rows + TROWS - 1) / TROWS;
      chunkOff[s+1] = ck;
    }
  }
}

// ---------------- t_emb ----------------
__global__ void k_temb(const int* __restrict__ t_pos, float* __restrict__ temb){
  int tid = threadIdx.x;
  if (tid >= B_*T_) return;
  int b = tid / T_, t = tid % T_;
  int p0 = t_pos[(b*T_+t)*2+0], p1 = t_pos[(b*T_+t)*2+1];
  float tp = (float)((p0 <= 4) ? p1 : 23 + p1);
  float c0 = -logf(10000.f)/32.f;
  for (int j = 0; j < 32; ++j){
    float a = tp * expf(c0 * (float)j);
    temb[(b*T_+t)*64 + j]      = cosf(a);
    temb[(b*T_+t)*64 + 32 + j] = sinf(a);
  }
}

// ---------------- core[b] ----------------
__global__ __launch_bounds__(256) void k_core(const float* __restrict__ temb,
                                              const float* __restrict__ core_W,
                                              const float* __restrict__ core_b,
                                              float* __restrict__ core_f){
  int idx = blockIdx.x*256 + threadIdx.x;
  if (idx >= B_*4096) return;
  int b = idx >> 12, c = idx & 4095;
  const float* te = temb + (b*T_ + 11)*64;
  float a = core_b[c];
  for (int h = 0; h < 64; ++h) a += te[h] * core_W[h*4096 + c];
  core_f[idx] = a;
}

// ---------------- tmp1[b] ----------------
__global__ __launch_bounds__(256) void k_tmp1(const int* __restrict__ ind,
                                              const float* __restrict__ nv_p1,
                                              const float* __restrict__ nv_pk,
                                              float* __restrict__ tmp1){
  int idx = blockIdx.x*256 + threadIdx.x;
  if (idx >= B_*4096) return;
  int b = idx >> 12, c = idx & 4095;
  int i0 = ind[(b*T_+1)*2+0], i1 = ind[(b*T_+1)*2+1];
  int row = (i0 <= 4) ? i1 : 23 + i1;
  const float* te = nv_p1 + row*64;
  float a = 0.f;
  for (int h = 0; h < 64; ++h) a += te[h] * nv_pk[h*4096 + c];
  tmp1[idx] = a;
}

// ---------------- Gsum = geo + geo@geo (clean re-test of R9 config) ----------
// gcn1's adjacency is data-independent: h + A h + A^2 h = h + (A+A^2) h.
// Batched loads: 8 loads per k-group of 4, unroll 2 -> 16 in flight, latency
// amortized. geo is 1MB, L2-resident.
__global__ __launch_bounds__(256) void k_geo2(const float* __restrict__ geo,
                                              float* __restrict__ gsum){
  __shared__ float srow[4][512];
  int n0 = blockIdx.x*4;
  int tid = threadIdx.x;
  for (int idx = tid; idx < 2048; idx += 256){
    int r = idx >> 9, k = idx & 511;
    srow[r][k] = (n0 + r < N_ && k < N_) ? geo[(n0+r)*N_ + k] : 0.f;
  }
  __syncthreads();
  float acc0[4] = {0.f,0.f,0.f,0.f};
  float acc1[4] = {0.f,0.f,0.f,0.f};
  int m0 = tid, m1 = tid + 256;
  bool v1 = (m1 < N_);
  #pragma unroll 2
  for (int k = 0; k < N_; k += 4){       // 500 % 4 == 0
    float a0 = geo[(k+0)*N_ + m0];
    float a1 = geo[(k+1)*N_ + m0];
    float a2 = geo[(k+2)*N_ + m0];
    float a3 = geo[(k+3)*N_ + m0];
    float b0 = v1 ? geo[(k+0)*N_ + m1] : 0.f;
    float b1 = v1 ? geo[(k+1)*N_ + m1] : 0.f;
    float b2 = v1 ? geo[(k+2)*N_ + m1] : 0.f;
    float b3 = v1 ? geo[(k+3)*N_ + m1] : 0.f;
    #pragma unroll
    for (int r = 0; r < 4; ++r){
      float s0 = srow[r][k], s1 = srow[r][k+1], s2 = srow[r][k+2], s3 = srow[r][k+3];
      acc0[r] += s0*a0 + s1*a1 + s2*a2 + s3*a3;
      acc1[r] += s0*b0 + s1*b1 + s2*b2 + s3*b3;
    }
  }
  #pragma unroll
  for (int r = 0; r < 4; ++r){
    int n = n0 + r;
    if (n < N_){
      gsum[n*N_+m0] = geo[n*N_+m0] + acc0[r];
      if (v1) gsum[n*N_+m1] = geo[n*N_+m1] + acc1[r];
    }
  }
}

// ---------------- TCN stage-1 precompute (PARALLEL: grid (20,81) x 128) ----------------
__global__ __launch_bounds__(128) void k_tprep(
    const float* __restrict__ temb,
    const float* __restrict__ fcx_W, const float* __restrict__ fcx_b,
    const float* __restrict__ WinN, const float* __restrict__ WinP,
    float* __restrict__ TE)
{
  int slot = blockIdx.x;
  int y = blockIdx.y;
  int k = slot >> 1, path = slot & 1;
  const float* Win = (path ? WinP : WinN) + k*16384;
  int o = threadIdx.x;
  if (y < 80){
    __shared__ float ste[64];
    int b = y/5, t = y%5;
    if (o < 64) ste[o] = temb[(b*T_ + t)*64 + o];
    __syncthreads();
    float acc = 0.f;
    for (int cc = 0; cc < 64; ++cc) acc += ste[cc] * Win[(64+cc)*128 + o];
    TE[slot*10240 + y*128 + o] = acc;
  } else {
    float a0=0.f, a1=0.f, c0=0.f;
    for (int c = 0; c < 64; ++c){
      float w = Win[c*128 + o];
      a0 += fcx_W[c]*w; a1 += fcx_W[64+c]*w; c0 += fcx_b[c]*w;
    }
    float* AAs = TE + 20*10240 + slot*384;
    AAs[o] = a0; AAs[128+o] = a1; AAs[256+o] = c0;
  }
}

// ---------------- TCN v4 (R4 WINNER, unchanged): compact list + balanced XCD --
__global__ __launch_bounds__(256) void k_tcn2(
    const float* __restrict__ x,
    const float* __restrict__ TE,
    const int* __restrict__ node_list, const int* __restrict__ off,
    const float* __restrict__ binN,
    const float* __restrict__ WfN,  const float* __restrict__ bfN,
    const float* __restrict__ WgN,  const float* __restrict__ bgN,
    const float* __restrict__ WoutN,const float* __restrict__ boutN,
    const float* __restrict__ binP,
    const float* __restrict__ WfP,  const float* __restrict__ bfP,
    const float* __restrict__ WgP,  const float* __restrict__ bgP,
    const float* __restrict__ WoutP,const float* __restrict__ boutP,
    float* __restrict__ out_unb, float* __restrict__ out_hpr)
{
  const int* chunkOff = off + 16;
  int nwork = chunkOff[2*K_];
  int q = (nwork + 7) >> 3;
  int id = blockIdx.x;
  int xcd = id & 7, pos = id >> 3;
  if (pos >= q) return;
  int w = xcd*q + pos;
  if (w >= nwork) return;
  int slot = 0;
  #pragma unroll 1
  while (chunkOff[slot+1] <= w) ++slot;
  int r0 = (w - chunkOff[slot]) * TROWS;

  int k = slot >> 1;
  int path = slot & 1;
  int cnt = off[k+1] - off[k];
  int rows = cnt * 16;
  if (r0 >= rows) return;

  const float* bin  = (path ? binP  : binN)  + k*128;
  const float* Wf   = (path ? WfP   : WfN)   + k*4*16384;
  const float* bf_  = (path ? bfP   : bfN)   + k*2*128;
  const float* Wg   = (path ? WgP   : WgN)   + k*4*16384;
  const float* bg_  = (path ? bgP   : bgN)   + k*2*128;
  const float* Wout = (path ? WoutP : WoutN) + k*8192;
  const float* bout = (path ? boutP : boutN) + k*64;
  float* outb = path ? out_hpr : out_unb;
  int t0 = path ? 0 : 1;

  __shared__ __align__(16) float sH0[TROWS*512];
  __shared__ __align__(16) float sH1[TROWS*256];
  __shared__ __align__(16) float sH2[TROWS*128];
  __shared__ float xs[TROWS][4][2];
  __shared__ int rowBN[TROWS];
  __shared__ int rowB[TROWS];

  int tid = threadIdx.x;
  if (tid < TROWS){
    int r = r0 + tid;
    if (r < rows){
      int node = node_list[off[k] + (r >> 4)];
      int b = r & 15;
      rowBN[tid] = b*N_ + node;
      rowB[tid]  = b;
    } else { rowBN[tid] = -1; rowB[tid] = 0; }
  }
  __syncthreads();
  if (tid < TROWS*4){
    int i = tid >> 2, tl = tid & 3;
    int rb = rowBN[i];
    float x0 = 0.f, x1 = 0.f;
    if (rb >= 0){
      const float* xp = x + (rb*T_ + tl + t0)*2;
      x0 = xp[0]; x1 = xp[1];
    }
    xs[i][tl][0] = x0; xs[i][tl][1] = x1;
  }
  __syncthreads();

  // Stage 1 (algebraic): h0 = x0*A0 + x1*A1 + C0 + TE[b][tl+t0] + bin
  {
    int o = tid & 127, half = tid >> 7;
    const float* AAs = TE + 20*10240 + slot*384;
    const float* TEs = TE + slot*10240;
    float a0 = AAs[o], a1 = AAs[128+o], c0 = AAs[256+o];
    float bn = bin[o];
    #pragma unroll
    for (int jj = 0; jj < 12; ++jj){
      int rt = half*12 + jj;
      int i = rt >> 2, tl = rt & 3;
      float v = xs[i][tl][0]*a0 + xs[i][tl][1]*a1 + c0
              + TEs[(rowB[i]*5 + tl + t0)*128 + o] + bn;
      sH0[rt*128 + o] = v;
    }
  }
  __syncthreads();

  // Stage 2: block0 (d=1), fused f+g, sH0 -> sH1.
  {
    int o = tid & 127;
    int jg = (tid >> 7)*6;
    float af[6], ag[6];
    #pragma unroll
    for (int j=0;j<6;++j){ af[j]=0.f; ag[j]=0.f; }
    for (int c = 0; c < 128; c += 4){
      float f00=Wf[(c+0)*128+o], f01=Wf[(c+1)*128+o], f02=Wf[(c+2)*128+o], f03=Wf[(c+3)*128+o];
      float f10=Wf[16384+(c+0)*128+o], f11=Wf[16384+(c+1)*128+o], f12=Wf[16384+(c+2)*128+o], f13=Wf[16384+(c+3)*128+o];
      float g00=Wg[(c+0)*128+o], g01=Wg[(c+1)*128+o], g02=Wg[(c+2)*128+o], g03=Wg[(c+3)*128+o];
      float g10=Wg[16384+(c+0)*128+o], g11=Wg[16384+(c+1)*128+o], g12=Wg[16384+(c+2)*128+o], g13=Wg[16384+(c+3)*128+o];
      #pragma unroll
      for (int jj=0;jj<6;++jj){
        int j = jg + jj;
        int i = j >> 1, ti = j & 1;
        float4 xa = *(const float4*)&sH0[(i*4+ti*2  )*128 + c];
        float4 xb = *(const float4*)&sH0[(i*4+ti*2+1)*128 + c];
        af[jj] += xa.x*f00 + xa.y*f01 + xa.z*f02 + xa.w*f03
                + xb.x*f10 + xb.y*f11 + xb.z*f12 + xb.w*f13;
        ag[jj] += xa.x*g00 + xa.y*g01 + xa.z*g02 + xa.w*g03
                + xb.x*g10 + xb.y*g11 + xb.z*g12 + xb.w*g13;
      }
    }
    float bfv = bf_[o], bgv = bg_[o];
    #pragma unroll
    for (int jj=0;jj<6;++jj){
      int j = jg + jj;
      int i = j >> 1, ti = j & 1;
      float f = tanhf(af[jj] + bfv);
      float g = 1.f/(1.f + expf(-(ag[jj] + bgv)));
      sH1[j*128 + o] = f*g + sH0[(i*4 + ti*2 + 1)*128 + o];
    }
  }
  __syncthreads();

  // Stage 3: block1 (d=2), fused f+g, sH1 -> sH2.
  {
    int o = tid & 127;
    int ig = (tid >> 7)*3;
    const float* Wf1 = Wf + 2*16384;
    const float* Wg1 = Wg + 2*16384;
    float af[3], ag[3];
    #pragma unroll
    for (int i=0;i<3;++i){ af[i]=0.f; ag[i]=0.f; }
    for (int c = 0; c < 128; c += 4){
      float f00=Wf1[(c+0)*128+o], f01=Wf1[(c+1)*128+o], f02=Wf1[(c+2)*128+o], f03=Wf1[(c+3)*128+o];
      float f10=Wf1[16384+(c+0)*128+o], f11=Wf1[16384+(c+1)*128+o], f12=Wf1[16384+(c+2)*128+o], f13=Wf1[16384+(c+3)*128+o];
      float g00=Wg1[(c+0)*128+o], g01=Wg1[(c+1)*128+o], g02=Wg1[(c+2)*128+o], g03=Wg1[(c+3)*128+o];
      float g10=Wg1[16384+(c+0)*128+o], g11=Wg1[16384+(c+1)*128+o], g12=Wg1[16384+(c+2)*128+o], g13=Wg1[16384+(c+3)*128+o];
      #pragma unroll
      for (int ii=0;ii<3;++ii){
        int i = ig + ii;
        float4 xa = *(const float4*)&sH1[(i*2+0)*128 + c];
        float4 xb = *(const float4*)&sH1[(i*2+1)*128 + c];
        af[ii] += xa.x*f00 + xa.y*f01 + xa.z*f02 + xa.w*f03
                + xb.x*f10 + xb.y*f11 + xb.z*f12 + xb.w*f13;
        ag[ii] += xa.x*g00 + xa.y*g01 + xa.z*g02 + xa.w*g03
                + xb.x*g10 + xb.y*g11 + xb.z*g12 + xb.w*g13;
      }
    }
    float bfv = bf_[128+o], bgv = bg_[128+o];
    #pragma unroll
    for (int ii=0;ii<3;++ii){
      int i = ig + ii;
      float f = tanhf(af[ii] + bfv);
      float g = 1.f/(1.f + expf(-(ag[ii] + bgv)));
      sH2[i*128 + o] = f*g + sH1[(i*2+1)*128 + o];
    }
  }
  __syncthreads();

  // Stage 4: out = h2 @ Wout + bout (128 -> 64)
  {
    int o6 = tid & 63, grp = tid >> 6;
    #pragma unroll
    for (int ii=0; ii<2; ++ii){
      int i = grp*2 + ii;
      if (i >= TROWS) continue;
      float acc = 0.f;
      for (int c = 0; c < 128; c += 4){
        float w0=Wout[(c+0)*64+o6], w1=Wout[(c+1)*64+o6],
              w2=Wout[(c+2)*64+o6], w3=Wout[(c+3)*64+o6];
        float4 xv = *(const float4*)&sH2[i*128 + c];
        acc += xv.x*w0 + xv.y*w1 + xv.z*w2 + xv.w*w3;
      }
      if (rowBN[i] >= 0) outb[rowBN[i]*64 + o6] = acc + bout[o6];
    }
  }
}

// ---------------- fused per-expert TCN (fallback when !useP) ----------------
__global__ __launch_bounds__(256) void k_tcn(
    const float* __restrict__ x,
    const float* __restrict__ fcx_W, const float* __restrict__ fcx_b,
    const float* __restrict__ temb,
    const int* __restrict__ node_list, const int* __restrict__ off,
    const float* __restrict__ WinN, const float* __restrict__ binN,
    const float* __restrict__ WfN,  const float* __restrict__ bfN,
    const float* __restrict__ WgN,  const float* __restrict__ bgN,
    const float* __restrict__ WoutN,const float* __restrict__ boutN,
    const float* __restrict__ WinP, const float* __restrict__ binP,
    const float* __restrict__ WfP,  const float* __restrict__ bfP,
    const float* __restrict__ WgP,  const float* __restrict__ bgP,
    const float* __restrict__ WoutP,const float* __restrict__ boutP,
    float* __restrict__ out_unb, float* __restrict__ out_hpr)
{
  int slot = blockIdx.x;
  int k = slot >> 1;
  int path = slot & 1;
  int cnt = off[k+1] - off[k];
  int rows = cnt * 16;
  int r0 = blockIdx.y * TROWS;
  if (r0 >= rows) return;

  const float* Win  = (path ? WinP  : WinN)  + k*16384;
  const float* bin  = (path ? binP  : binN)  + k*128;
  const float* Wf   = (path ? WfP   : WfN)   + k*4*16384;
  const float* bf_  = (path ? bfP   : bfN)   + k*2*128;
  const float* Wg   = (path ? WgP   : WgN)   + k*4*16384;
  const float* bg_  = (path ? bgP   : bgN)   + k*2*128;
  const float* Wout = (path ? WoutP : WoutN) + k*8192;
  const float* bout = (path ? boutP : boutN) + k*64;
  float* outb = path ? out_hpr : out_unb;
  int t0 = path ? 0 : 1;

  __shared__ __align__(16) float sIn[TROWS*512];
  __shared__ __align__(16) float sH0[TROWS*512];
  __shared__ __align__(16) float sH1[TROWS*256];
  __shared__ __align__(16) float sH2[TROWS*128];
  __shared__ int rowBN[TROWS];
  __shared__ int rowB[TROWS];

  int tid = threadIdx.x;
  if (tid < TROWS){
    int r = r0 + tid;
    if (r < rows){
      int node = node_list[off[k] + (r >> 4)];
      int b = r & 15;
      rowBN[tid] = b*N_ + node;
      rowB[tid]  = b;
    } else { rowBN[tid] = -1; rowB[tid] = 0; }
  }
  __syncthreads();

  for (int i = 0; i < TROWS; ++i){
    int rb = rowBN[i], b = rowB[i];
    for (int c2 = tid; c2 < 512; c2 += 256){
      int t = (c2 >> 7) + t0, c = c2 & 127;
      float v = 0.f;
      if (rb >= 0){
        if (c < 64){
          const float* xp = x + (rb*T_ + t)*2;
          v = xp[0]*fcx_W[c] + xp[1]*fcx_W[64+c] + fcx_b[c];
        } else {
          v = temb[(b*T_ + t)*64 + (c-64)];
        }
      }
      sIn[i*512 + c2] = v;
    }
  }
  __syncthreads();

  {
    int oc = (tid & 63)*2;
    int jg = (tid >> 6)*6;
    float a0[6], a1[6];
    #pragma unroll
    for (int j=0;j<6;++j){ a0[j]=0.f; a1[j]=0.f; }
    for (int c = 0; c < 128; c += 4){
      float2 w0 = *(const float2*)(Win + (c+0)*128 + oc);
      float2 w1 = *(const float2*)(Win + (c+1)*128 + oc);
      float2 w2 = *(const float2*)(Win + (c+2)*128 + oc);
      float2 w3 = *(const float2*)(Win + (c+3)*128 + oc);
      #pragma unroll
      for (int j=0;j<6;++j){
        float4 xv = *(const float4*)&sIn[(jg+j)*128 + c];
        a0[j] += xv.x*w0.x + xv.y*w1.x + xv.z*w2.x + xv.w*w3.x;
        a1[j] += xv.x*w0.y + xv.y*w1.y + xv.z*w2.y + xv.w*w3.y;
      }
    }
    float b0v = bin[oc], b1v = bin[oc+1];
    #pragma unroll
    for (int j=0;j<6;++j){
      sH0[(jg+j)*128 + oc]   = a0[j] + b0v;
      sH0[(jg+j)*128 + oc+1] = a1[j] + b1v;
    }
  }
  __syncthreads();

  {
    int o = tid & 127;
    int jg = (tid >> 7)*6;
    float af[6], ag[6];
    #pragma unroll
    for (int j=0;j<6;++j){ af[j]=0.f; ag[j]=0.f; }
    for (int c = 0; c < 128; c += 4){
      float f00=Wf[(c+0)*128+o], f01=Wf[(c+1)*128+o], f02=Wf[(c+2)*128+o], f03=Wf[(c+3)*128+o];
      float f10=Wf[16384+(c+0)*128+o], f11=Wf[16384+(c+1)*128+o], f12=Wf[16384+(c+2)*128+o], f13=Wf[16384+(c+3)*128+o];
      float g00=Wg[(c+0)*128+o], g01=Wg[(c+1)*128+o], g02=Wg[(c+2)*128+o], g03=Wg[(c+3)*128+o];
      float g10=Wg[16384+(c+0)*128+o], g11=Wg[16384+(c+1)*128+o], g12=Wg[16384+(c+2)*128+o], g13=Wg[16384+(c+3)*128+o];
      #pragma unroll
      for (int jj=0;jj<6;++jj){
        int j = jg + jj;
        int i = j >> 1, ti = j & 1;
        float4 xa = *(const float4*)&sH0[(i*4+ti*2  )*128 + c];
        float4 xb = *(const float4*)&sH0[(i*4+ti*2+1)*128 + c];
        af[jj] += xa.x*f00 + xa.y*f01 + xa.z*f02 + xa.w*f03
                + xb.x*f10 + xb.y*f11 + xb.z*f12 + xb.w*f13;
        ag[jj] += xa.x*g00 + xa.y*g01 + xa.z*g02 + xa.w*g03
                + xb.x*g10 + xb.y*g11 + xb.z*g12 + xb.w*g13;
      }
    }
    float bfv = bf_[o], bgv = bg_[o];
    #pragma unroll
    for (int jj=0;jj<6;++jj){
      int j = jg + jj;
      int i = j >> 1, ti = j & 1;
      float f = tanhf(af[jj] + bfv);
      float g = 1.f/(1.f + expf(-(ag[jj] + bgv)));
      sH1[j*128 + o] = f*g + sH0[(i*4 + ti*2 + 1)*128 + o];
    }
  }
  __syncthreads();

  {
    int o = tid & 127;
    int ig = (tid >> 7)*3;
    const float* Wf1 = Wf + 2*16384;
    const float* Wg1 = Wg + 2*16384;
    float af[3], ag[3];
    #pragma unroll
    for (int i=0;i<3;++i){ af[i]=0.f; ag[i]=0.f; }
    for (int c = 0; c < 128; c += 4){
      float f00=Wf1[(c+0)*128+o], f01=Wf1[(c+1)*128+o], f02=Wf1[(c+2)*128+o], f03=Wf1[(c+3)*128+o];
      float f10=Wf1[16384+(c+0)*128+o], f11=Wf1[16384+(c+1)*128+o], f12=Wf1[16384+(c+2)*128+o], f13=Wf1[16384+(c+3)*128+o];
      float g00=Wg1[(c+0)*128+o], g01=Wg1[(c+1)*128+o], g02=Wg1[(c+2)*128+o], g03=Wg1[(c+3)*128+o];
      float g10=Wg1[16384+(c+0)*128+o], g11=Wg1[16384+(c+1)*128+o], g12=Wg1[16384+(c+2)*128+o], g13=Wg1[16384+(c+3)*128+o];
      #pragma unroll
      for (int ii=0;ii<3;++ii){
        int i = ig + ii;
        float4 xa = *(const float4*)&sH1[(i*2+0)*128 + c];
        float4 xb = *(const float4*)&sH1[(i*2+1)*128 + c];
        af[ii] += xa.x*f00 + xa.y*f01 + xa.z*f02 + xa.w*f03
                + xb.x*f10 + xb.y*f11 + xb.z*f12 + xb.w*f13;
        ag[ii] += xa.x*g00 + xa.y*g01 + xa.z*g02 + xa.w*g03
                + xb.x*g10 + xb.y*g11 + xb.z*g12 + xb.w*g13;
      }
    }
    float bfv = bf_[128+o], bgv = bg_[128+o];
    #pragma unroll
    for (int ii=0;ii<3;++ii){
      int i = ig + ii;
      float f = tanhf(af[ii] + bfv);
      float g = 1.f/(1.f + expf(-(ag[ii] + bgv)));
      sH2[i*128 + o] = f*g + sH1[(i*2+1)*128 + o];
    }
  }
  __syncthreads();

  {
    int o6 = tid & 63, grp = tid >> 6;
    #pragma unroll
    for (int ii=0; ii<2; ++ii){
      int i = grp*2 + ii;
      if (i >= TROWS) continue;
      float acc = 0.f;
      for (int c = 0; c < 128; c += 4){
        float w0=Wout[(c+0)*64+o6], w1=Wout[(c+1)*64+o6],
              w2=Wout[(c+2)*64+o6], w3=Wout[(c+3)*64+o6];
        float4 xv = *(const float4*)&sH2[i*128 + c];
        acc += xv.x*w0 + xv.y*w1 + xv.z*w2 + xv.w*w3;
      }
      if (rowBN[i] >= 0) outb[rowBN[i]*64 + o6] = acc + bout[o6];
    }
  }
}

// ---------------- batchnorm ----------------
__global__ __launch_bounds__(256) void k_bnstats(const float* __restrict__ unb,
                                                 const float* __restrict__ hpr,
                                                 float* __restrict__ stats){
  int bid = blockIdx.x;
  int tensor = bid >> 6, c = bid & 63;
  const float* buf = tensor ? hpr : unb;
  float s1 = 0.f, s2 = 0.f;
  for (int r = threadIdx.x; r < NROWS; r += 256){
    float v = buf[r*64 + c];
    s1 += v; s2 += v*v;
  }
  __shared__ float r1[256], r2[256];
  r1[threadIdx.x]=s1; r2[threadIdx.x]=s2;
  __syncthreads();
  for (int s=128; s>0; s>>=1){
    if (threadIdx.x < s){ r1[threadIdx.x]+=r1[threadIdx.x+s]; r2[threadIdx.x]+=r2[threadIdx.x+s]; }
    __syncthreads();
  }
  if (threadIdx.x==0){
    float mean = r1[0]/(float)NROWS;
    float var  = r2[0]/(float)NROWS - mean*mean;
    stats[tensor*128 + c]      = mean;
    stats[tensor*128 + 64 + c] = rsqrtf(var + 1e-5f);
  }
}

// R7: float4 vectorized (grid 1000). 64%4==0 so a quad never wraps c.
__global__ __launch_bounds__(256) void k_bnapply(float* __restrict__ unb, float* __restrict__ hpr,
                                                 const float* __restrict__ stats,
                                                 const float* __restrict__ g1, const float* __restrict__ be1,
                                                 const float* __restrict__ gP, const float* __restrict__ beP){
  int idx = blockIdx.x*256 + threadIdx.x;          // one float4
  if (idx >= 2*NROWS*16) return;
  int tensor = idx >= NROWS*16;
  int local4 = idx - tensor*NROWS*16;
  int base = local4*4;
  int c = base & 63;
  float* buf = tensor ? hpr : unb;
  float4 v    = *(float4*)&buf[base];
  float4 mean = *(const float4*)&stats[tensor*128 + c];
  float4 rstd = *(const float4*)&stats[tensor*128 + 64 + c];
  float4 g    = tensor ? *(const float4*)&gP[c]  : *(const float4*)&g1[c];
  float4 bb   = tensor ? *(const float4*)&beP[c] : *(const float4*)&be1[c];
  v.x = g.x*(v.x-mean.x)*rstd.x + bb.x;
  v.y = g.y*(v.y-mean.y)*rstd.y + bb.y;
  v.z = g.z*(v.z-mean.z)*rstd.z + bb.z;
  v.w = g.w*(v.w-mean.w)*rstd.w + bb.w;
  *(float4*)&buf[base] = v;
}

// ---------------- flash attn, 16 rows/block, 2 rows/thread ----------------
// R6: PV 4-dim x 32-m tiling. R7: float4 staging. R9/R11: FINAL semantics:
// 0 = write Y; 1 = final with Z1 residual; 2 = final WITHOUT Z1 (fused gcn1:
// cur = (Gsum@X + X0)@Wg + bg, Gsum = geo+geo^2 precomputed by k_geo2).
template<int AMODE, int RELU, int FINAL, int ADD>
__global__ __launch_bounds__(256) void k_attn(
    const float* __restrict__ geo,
    const float* __restrict__ Qf, const float* __restrict__ Qb,
    const float* __restrict__ M,
    const float* __restrict__ Keysf, const float* __restrict__ Keysb,
    const float* __restrict__ X,
    const float* __restrict__ X0, const float* __restrict__ Z1,
    const float* __restrict__ Wg, const float* __restrict__ bg,
    float* __restrict__ cur, float* __restrict__ Y)
{
  __shared__ __align__(16) float kbuf[64][65];
  __shared__ __align__(16) float xbuf[64][64];
  __shared__ __align__(16) float vbuf[16][64];
  __shared__ __align__(16) float pbuf[16][64];

  int b = blockIdx.y, n0 = blockIdx.x*16;
  int tid = threadIdx.x;
  int nl = tid >> 5, ml = tid & 31;
  int nA = n0 + nl, nB = n0 + nl + 8;
  int mh = (ml >> 4) << 5;       // 0 or 32: m-half this lane owns in PV
  int d0 = (ml & 15) * 4;        // 4 output dims this lane owns in PV
  const float4 f40 = {0.f,0.f,0.f,0.f};
  float4 rrK4[4], rrX4[4], rrA4;

  if (AMODE != 0){
    {
      int r = tid >> 4, k4 = (tid & 15) * 4;   // 256 f4 = 1024 floats (16 rows x 64)
      int nn = n0 + r;
      float4 qv = f40;
      if (nn < N_){
        const float* qp = (AMODE == 1) ? &Qf[(b*N_+nn)*64+k4] : &Qb[nn*64+k4];
        qv = *(const float4*)qp;
      }
      *(float4*)&pbuf[r][k4] = qv;
    }
    #pragma unroll
    for (int ii = 0; ii < 4; ++ii){
      int fidx = tid + ii*256;                 // 1024 f4 = 4096 floats
      int r = fidx >> 4, k4 = (fidx & 15)*4;
      float4 v = *(const float4*)&M[b*4096 + r*64 + k4];
      kbuf[r][k4+0]=v.x; kbuf[r][k4+1]=v.y; kbuf[r][k4+2]=v.z; kbuf[r][k4+3]=v.w;
    }
    __syncthreads();
    float vxA = 0.f, vyA = 0.f, vxB = 0.f, vyB = 0.f;
    for (int kk = 0; kk < 64; ++kk){
      float qA = pbuf[nl][kk], qB = pbuf[nl+8][kk];
      float2 m2 = *(const float2*)&kbuf[kk][ml*2];
      vxA += qA*m2.x; vyA += qA*m2.y;
      vxB += qB*m2.x; vyB += qB*m2.y;
    }
    __syncthreads();
    vbuf[nl  ][ml*2] = vxA; vbuf[nl  ][ml*2+1] = vyA;
    vbuf[nl+8][ml*2] = vxB; vbuf[nl+8][ml*2+1] = vyB;
  }
  {
    if (AMODE != 0) __syncthreads();
    #pragma unroll
    for (int ii = 0; ii < 4; ++ii){
      int fidx = tid + ii*256;
      int mm = fidx >> 4, k4 = (fidx & 15)*4;
      if (AMODE != 0){
        const float* kp = (AMODE == 1) ? &Keysf[(b*N_+mm)*64+k4] : &Keysb[mm*64+k4];
        float4 kv = *(const float4*)kp;
        kbuf[mm][k4+0]=kv.x; kbuf[mm][k4+1]=kv.y; kbuf[mm][k4+2]=kv.z; kbuf[mm][k4+3]=kv.w;
      }
      *(float4*)&xbuf[mm][k4] = *(const float4*)&X[(b*N_+mm)*64+k4];
    }
    if (AMODE == 0){
      int r = tid >> 4, m4 = (tid & 15)*4;     // 256 f4 = 16 rows x 64 m
      int nn = n0 + r;
      float4 g0 = (nn < N_) ? *(const float4*)&geo[nn*N_ + m4] : f40;
      *(float4*)&pbuf[r][m4] = g0;
    }
    __syncthreads();
  }

  float m_runA = -1e30f, l_runA = 0.f;
  float m_runB = -1e30f, l_runB = 0.f;
  float accA[4] = {0.f,0.f,0.f,0.f};
  float accB[4] = {0.f,0.f,0.f,0.f};

  for (int ci = 0; ci < 8; ++ci){
    int m0 = ci*64;
    if (ci < 7){
      #pragma unroll
      for (int ii=0; ii<4; ++ii){
        int fidx = tid + ii*256;
        int mm = fidx >> 4, k4 = (fidx & 15)*4;
        int m = m0 + 64 + mm;
        if (AMODE != 0){
          if (m < N_){
            const float* kp = (AMODE == 1) ? &Keysf[(b*N_+m)*64+k4] : &Keysb[m*64+k4];
            rrK4[ii] = *(const float4*)kp;
          } else rrK4[ii] = f40;
        }
        rrX4[ii] = (m < N_) ? *(const float4*)&X[(b*N_+m)*64+k4] : f40;
      }
      if (AMODE == 0){
        int r = tid >> 4, m4 = (tid & 15)*4;
        int nn = n0 + r, m = m0 + 64 + m4;
        rrA4 = (nn < N_ && m < N_) ? *(const float4*)&geo[nn*N_ + m] : f40;
      }
    }
    if (AMODE != 0){
      float s0A = 0.f, s1A = 0.f, s0B = 0.f, s1B = 0.f;
      for (int kk = 0; kk < 64; kk += 4){
        float4 qA = *(const float4*)&vbuf[nl  ][kk];
        float4 qB = *(const float4*)&vbuf[nl+8][kk];
        float4 k0 = *(const float4*)&kbuf[ml   ][kk];
        float4 k1 = *(const float4*)&kbuf[ml+32][kk];
        s0A += qA.x*k0.x + qA.y*k0.y + qA.z*k0.z + qA.w*k0.w;
        s1A += qA.x*k1.x + qA.y*k1.y + qA.z*k1.z + qA.w*k1.w;
        s0B += qB.x*k0.x + qB.y*k0.y + qB.z*k0.z + qB.w*k0.w;
        s1B += qB.x*k1.x + qB.y*k1.y + qB.z*k1.z + qB.w*k1.w;
      }
      float v0A = (m0 + ml      < N_) ? (RELU ? fmaxf(s0A, 0.f) : s0A) : -1e30f;
      float v1A = (m0 + ml + 32 < N_) ? (RELU ? fmaxf(s1A, 0.f) : s1A) : -1e30f;
      float v0B = (m0 + ml      < N_) ? (RELU ? fmaxf(s0B, 0.f) : s0B) : -1e30f;
      float v1B = (m0 + ml + 32 < N_) ? (RELU ? fmaxf(s1B, 0.f) : s1B) : -1e30f;
      float cmaxA = fmaxf(v0A, v1A), cmaxB = fmaxf(v0B, v1B);
      #pragma unroll
      for (int msk = 1; msk < 32; msk <<= 1){
        cmaxA = fmaxf(cmaxA, __shfl_xor(cmaxA, msk, 32));
        cmaxB = fmaxf(cmaxB, __shfl_xor(cmaxB, msk, 32));
      }
      float mnewA = fmaxf(m_runA, cmaxA), mnewB = fmaxf(m_runB, cmaxB);
      float scaleA = expf(m_runA - mnewA), scaleB = expf(m_runB - mnewB);
      float p0A = expf(v0A - mnewA), p1A = expf(v1A - mnewA);
      float p0B = expf(v0B - mnewB), p1B = expf(v1B - mnewB);
      float lcA = p0A + p1A, lcB = p0B + p1B;
      #pragma unroll
      for (int msk = 1; msk < 32; msk <<= 1){
        lcA += __shfl_xor(lcA, msk, 32);
        lcB += __shfl_xor(lcB, msk, 32);
      }
      l_runA = l_runA*scaleA + lcA; m_runA = mnewA;
      l_runB = l_runB*scaleB + lcB; m_runB = mnewB;
      #pragma unroll
      for (int d=0; d<4; ++d){ accA[d] *= scaleA; accB[d] *= scaleB; }
      pbuf[nl  ][ml]    = p0A;
      pbuf[nl  ][ml+32] = p1A;
      pbuf[nl+8][ml]    = p0B;
      pbuf[nl+8][ml+32] = p1B;
    }
    __syncthreads();
    #pragma unroll
    for (int mm = 0; mm < 32; mm += 4){
      float4 pA = *(const float4*)&pbuf[nl  ][mh + mm];
      float4 pB = *(const float4*)&pbuf[nl+8][mh + mm];
      float4 x0 = *(const float4*)&xbuf[mh+mm+0][d0];
      float4 x1 = *(const float4*)&xbuf[mh+mm+1][d0];
      float4 x2 = *(const float4*)&xbuf[mh+mm+2][d0];
      float4 x3 = *(const float4*)&xbuf[mh+mm+3][d0];
      accA[0] += pA.x*x0.x + pA.y*x1.x + pA.z*x2.x + pA.w*x3.x;
      accA[1] += pA.x*x0.y + pA.y*x1.y + pA.z*x2.y + pA.w*x3.y;
      accA[2] += pA.x*x0.z + pA.y*x1.z + pA.z*x2.z + pA.w*x3.z;
      accA[3] += pA.x*x0.w + pA.y*x1.w + pA.z*x2.w + pA.w*x3.w;
      accB[0] += pB.x*x0.x + pB.y*x1.x + pB.z*x2.x + pB.w*x3.x;
      accB[1] += pB.x*x0.y + pB.y*x1.y + pB.z*x2.y + pB.w*x3.y;
      accB[2] += pB.x*x0.z + pB.y*x1.z + pB.z*x2.z + pB.w*x3.z;
      accB[3] += pB.x*x0.w + pB.y*x1.w + pB.z*x2.w + pB.w*x3.w;
    }
    __syncthreads();
    if (ci < 7){
      #pragma unroll
      for (int ii=0; ii<4; ++ii){
        int fidx = tid + ii*256;
        int mm = fidx >> 4, k4 = (fidx & 15)*4;
        if (AMODE != 0){
          float4 kv = rrK4[ii];
          kbuf[mm][k4+0]=kv.x; kbuf[mm][k4+1]=kv.y; kbuf[mm][k4+2]=kv.z; kbuf[mm][k4+3]=kv.w;
        }
        *(float4*)&xbuf[mm][k4] = rrX4[ii];
      }
      if (AMODE == 0){
        int r = tid >> 4, m4 = (tid & 15)*4;
        *(float4*)&pbuf[r][m4] = rrA4;
      }
      __syncthreads();
    }
  }
  // recombine the two m-halves (lane pairs ml, ml^16 share nl)
  #pragma unroll
  for (int d=0; d<4; ++d){
    accA[d] += __shfl_xor(accA[d], 16, 32);
    accB[d] += __shfl_xor(accB[d], 16, 32);
  }
  if (AMODE != 0){
    float invA = 1.f / l_runA, invB = 1.f / l_runB;
    #pragma unroll
    for (int d=0; d<4; ++d){ accA[d] *= invA; accB[d] *= invB; }
  }

  if (!FINAL){
    if (ml < 16){
      if (nA < N_){
        float4 o4; o4.x = accA[0]; o4.y = accA[1]; o4.z = accA[2]; o4.w = accA[3];
        *(float4*)&Y[(b*N_+nA)*64 + d0] = o4;
      }
      if (nB < N_){
        float4 o4; o4.x = accB[0]; o4.y = accB[1]; o4.z = accB[2]; o4.w = accB[3];
        *(float4*)&Y[(b*N_+nB)*64 + d0] = o4;
      }
    }
    return;
  }

  {
    if (ml < 16){
      float4 svA = {0.f,0.f,0.f,0.f}, svB = {0.f,0.f,0.f,0.f};
      if (nA < N_){
        int row = b*N_ + nA;
        float4 x0v = *(const float4*)&X0[row*64 + d0];
        svA.x = accA[0] + x0v.x;
        svA.y = accA[1] + x0v.y;
        svA.z = accA[2] + x0v.z;
        svA.w = accA[3] + x0v.w;
        if (FINAL == 1){
          float4 z1v = *(const float4*)&Z1[row*64 + d0];
          svA.x += z1v.x; svA.y += z1v.y; svA.z += z1v.z; svA.w += z1v.w;
        }
      }
      if (nB < N_){
        int row = b*N_ + nB;
        float4 x0v = *(const float4*)&X0[row*64 + d0];
        svB.x = accB[0] + x0v.x;
        svB.y = accB[1] + x0v.y;
        svB.z = accB[2] + x0v.z;
        svB.w = accB[3] + x0v.w;
        if (FINAL == 1){
          float4 z1v = *(const float4*)&Z1[row*64 + d0];
          svB.x += z1v.x; svB.y += z1v.y; svB.z += z1v.z; svB.w += z1v.w;
        }
      }
      *(float4*)&vbuf[nl  ][d0] = svA;
      *(float4*)&vbuf[nl+8][d0] = svB;
    }
    #pragma unroll
    for (int ii = 0; ii < 4; ++ii){
      int fidx = tid + ii*256;
      int r = fidx >> 4, k4 = (fidx & 15)*4;
      float4 wv = *(const float4*)&Wg[r*64 + k4];
      kbuf[r][k4+0]=wv.x; kbuf[r][k4+1]=wv.y; kbuf[r][k4+2]=wv.z; kbuf[r][k4+3]=wv.w;
    }
    __syncthreads();
    float oxA = 0.f, oyA = 0.f, oxB = 0.f, oyB = 0.f;
    for (int kk = 0; kk < 64; ++kk){
      float sA = vbuf[nl][kk], sB = vbuf[nl+8][kk];
      float2 w2 = *(const float2*)&kbuf[kk][ml*2];
      oxA += sA*w2.x; oyA += sA*w2.y;
      oxB += sB*w2.x; oyB += sB*w2.y;
    }
    float2 bv = *(const float2*)&bg[ml*2];
    if (nA < N_){
      int row = b*N_ + nA;
      float vx = oxA + bv.x, vy = oyA + bv.y;
      if (ADD){
        float2 old = *(const float2*)&cur[row*64 + ml*2];
        vx += old.x; vy += old.y;
      }
      float2 o2; o2.x = vx; o2.y = vy;
      *(float2*)&cur[row*64 + ml*2] = o2;
    }
    if (nB < N_){
      int row = b*N_ + nB;
      float vx = oxB + bv.x, vy = oyB + bv.y;
      if (ADD){
        float2 old = *(const float2*)&cur[row*64 + ml*2];
        vx += old.x; vy += old.y;
      }
      float2 o2; o2.x = vx; o2.y = vy;
      *(float2*)&cur[row*64 + ml*2] = o2;
    }
  }
}

// ---------------- pass 1 with raw-score caching (16 rows/block) ----------------
template<int AMODE, int RELU>
__global__ __launch_bounds__(256) void k_attn_p1(
    const float* __restrict__ Qf, const float* __restrict__ Qb,
    const float* __restrict__ M,
    const float* __restrict__ Keysf, const float* __restrict__ Keysb,
    const float* __restrict__ X,
    float* __restrict__ Pb, float* __restrict__ Y)
{
  __shared__ __align__(16) float kbuf[64][65];
  __shared__ __align__(16) float xbuf[64][64];
  __shared__ __align__(16) float vbuf[16][64];
  __shared__ __align__(16) float pbuf[16][64];

  int b = blockIdx.y, n0 = blockIdx.x*16;
  int tid = threadIdx.x;
  int nl = tid >> 5, ml = tid & 31;
  int nA = n0 + nl, nB = n0 + nl + 8;
  int mh = (ml >> 4) << 5;
  int d0 = (ml & 15) * 4;
  const float4 f40 = {0.f,0.f,0.f,0.f};
  float4 rrK4[4], rrX4[4];

  {
    int r = tid >> 4, k4 = (tid & 15) * 4;
    int nn = n0 + r;
    float4 qv = f40;
    if (nn < N_){
      const float* qp = (AMODE == 1) ? &Qf[(b*N_+nn)*64+k4] : &Qb[nn*64+k4];
      qv = *(const float4*)qp;
    }
    *(float4*)&pbuf[r][k4] = qv;
  }
  #pragma unroll
  for (int ii = 0; ii < 4; ++ii){
    int fidx = tid + ii*256;
    int r = fidx >> 4, k4 = (fidx & 15)*4;
    float4 v = *(const float4*)&M[b*4096 + r*64 + k4];
    kbuf[r][k4+0]=v.x; kbuf[r][k4+1]=v.y; kbuf[r][k4+2]=v.z; kbuf[r][k4+3]=v.w;
  }
  __syncthreads();
  float vxA = 0.f, vyA = 0.f, vxB = 0.f, vyB = 0.f;
  for (int kk = 0; kk < 64; ++kk){
    float qA = pbuf[nl][kk], qB = pbuf[nl+8][kk];
    float2 m2 = *(const float2*)&kbuf[kk][ml*2];
    vxA += qA*m2.x; vyA += qA*m2.y;
    vxB += qB*m2.x; vyB += qB*m2.y;
  }
  __syncthreads();
  vbuf[nl  ][ml*2] = vxA; vbuf[nl  ][ml*2+1] = vyA;
  vbuf[nl+8][ml*2] = vxB; vbuf[nl+8][ml*2+1] = vyB;
  __syncthreads();
  #pragma unroll
  for (int ii = 0; ii < 4; ++ii){
    int fidx = tid + ii*256;
    int mm = fidx >> 4, k4 = (fidx & 15)*4;
    const float* kp = (AMODE == 1) ? &Keysf[(b*N_+mm)*64+k4] : &Keysb[mm*64+k4];
    float4 kv = *(const float4*)kp;
    kbuf[mm][k4+0]=kv.x; kbuf[mm][k4+1]=kv.y; kbuf[mm][k4+2]=kv.z; kbuf[mm][k4+3]=kv.w;
    *(float4*)&xbuf[mm][k4] = *(const float4*)&X[(b*N_+mm)*64+k4];
  }
  __syncthreads();

  float m_runA = -1e30f, l_runA = 0.f;
  float m_runB = -1e30f, l_runB = 0.f;
  float accA[4] = {0.f,0.f,0.f,0.f};
  float accB[4] = {0.f,0.f,0.f,0.f};

  for (int ci = 0; ci < 8; ++ci){
    int m0 = ci*64;
    if (ci < 7){
      #pragma unroll
      for (int ii=0; ii<4; ++ii){
        int fidx = tid + ii*256;
        int mm = fidx >> 4, k4 = (fidx & 15)*4;
        int m = m0 + 64 + mm;
        if (m < N_){
          const float* kp = (AMODE == 1) ? &Keysf[(b*N_+m)*64+k4] : &Keysb[m*64+k4];
          rrK4[ii] = *(const float4*)kp;
          rrX4[ii] = *(const float4*)&X[(b*N_+m)*64+k4];
        } else { rrK4[ii] = f40; rrX4[ii] = f40; }
      }
    }
    {
      float s0A = 0.f, s1A = 0.f, s0B = 0.f, s1B = 0.f;
      for (int kk = 0; kk < 64; kk += 4){
        float4 qA = *(const float4*)&vbuf[nl  ][kk];
        float4 qB = *(const float4*)&vbuf[nl+8][kk];
        float4 k0 = *(const float4*)&kbuf[ml   ][kk];
        float4 k1 = *(const float4*)&kbuf[ml+32][kk];
        s0A += qA.x*k0.x + qA.y*k0.y + qA.z*k0.z + qA.w*k0.w;
        s1A += qA.x*k1.x + qA.y*k1.y + qA.z*k1.z + qA.w*k1.w;
        s0B += qB.x*k0.x + qB.y*k0.y + qB.z*k0.z + qB.w*k0.w;
        s1B += qB.x*k1.x + qB.y*k1.y + qB.z*k1.z + qB.w*k1.w;
      }
      float v0A = (m0 + ml      < N_) ? (RELU ? fmaxf(s0A, 0.f) : s0A) : -1e30f;
      float v1A = (m0 + ml + 32 < N_) ? (RELU ? fmaxf(s1A, 0.f) : s1A) : -1e30f;
      float v0B = (m0 + ml      < N_) ? (RELU ? fmaxf(s0B, 0.f) : s0B) : -1e30f;
      float v1B = (m0 + ml + 32 < N_) ? (RELU ? fmaxf(s1B, 0.f) : s1B) : -1e30f;
      if (nA < N_){
        Pb[((long)(b*N_+nA))*512 + m0 + ml]      = v0A;
        Pb[((long)(b*N_+nA))*512 + m0 + ml + 32] = v1A;
      }
      if (nB < N_){
        Pb[((long)(b*N_+nB))*512 + m0 + ml]      = v0B;
        Pb[((long)(b*N_+nB))*512 + m0 + ml + 32] = v1B;
      }
      float cmaxA = fmaxf(v0A, v1A), cmaxB = fmaxf(v0B, v1B);
      #pragma unroll
      for (int msk = 1; msk < 32; msk <<= 1){
        cmaxA = fmaxf(cmaxA, __shfl_xor(cmaxA, msk, 32));
        cmaxB = fmaxf(cmaxB, __shfl_xor(cmaxB, msk, 32));
      }
      float mnewA = fmaxf(m_runA, cmaxA), mnewB = fmaxf(m_runB, cmaxB);
      float scaleA = expf(m_runA - mnewA), scaleB = expf(m_runB - mnewB);
      float p0A = expf(v0A - mnewA), p1A = expf(v1A - mnewA);
      float p0B = expf(v0B - mnewB), p1B = expf(v1B - mnewB);
      float lcA = p0A + p1A, lcB = p0B + p1B;
      #pragma unroll
      for (int msk = 1; msk < 32; msk <<= 1){
        lcA += __shfl_xor(lcA, msk, 32);
        lcB += __shfl_xor(lcB, msk, 32);
      }
      l_runA = l_runA*scaleA + lcA; m_runA = mnewA;
      l_runB = l_runB*scaleB + lcB; m_runB = mnewB;
      #pragma unroll
      for (int d=0; d<4; ++d){ accA[d] *= scaleA; accB[d] *= scaleB; }
      pbuf[nl  ][ml]    = p0A;
      pbuf[nl  ][ml+32] = p1A;
      pbuf[nl+8][ml]    = p0B;
      pbuf[nl+8][ml+32] = p1B;
    }
    __syncthreads();
    #pragma unroll
    for (int mm = 0; mm < 32; mm += 4){
      float4 pA = *(const float4*)&pbuf[nl  ][mh + mm];
      float4 pB = *(const float4*)&pbuf[nl+8][mh + mm];
      float4 x0 = *(const float4*)&xbuf[mh+mm+0][d0];
      float4 x1 = *(const float4*)&xbuf[mh+mm+1][d0];
      float4 x2 = *(const float4*)&xbuf[mh+mm+2][d0];
      float4 x3 = *(const float4*)&xbuf[mh+mm+3][d0];
      accA[0] += pA.x*x0.x + pA.y*x1.x + pA.z*x2.x + pA.w*x3.x;
      accA[1] += pA.x*x0.y + pA.y*x1.y + pA.z*x2.y + pA.w*x3.y;
      accA[2] += pA.x*x0.z + pA.y*x1.z + pA.z*x2.z + pA.w*x3.z;
      accA[3] += pA.x*x0.w + pA.y*x1.w + pA.z*x2.w + pA.w*x3.w;
      accB[0] += pB.x*x0.x + pB.y*x1.x + pB.z*x2.x + pB.w*x3.x;
      accB[1] += pB.x*x0.y + pB.y*x1.y + pB.z*x2.y + pB.w*x3.y;
      accB[2] += pB.x*x0.z + pB.y*x1.z + pB.z*x2.z + pB.w*x3.z;
      accB[3] += pB.x*x0.w + pB.y*x1.w + pB.z*x2.w + pB.w*x3.w;
    }
    __syncthreads();
    if (ci < 7){
      #pragma unroll
      for (int ii=0; ii<4; ++ii){
        int fidx = tid + ii*256;
        int mm = fidx >> 4, k4 = (fidx & 15)*4;
        float4 kv = rrK4[ii];
        kbuf[mm][k4+0]=kv.x; kbuf[mm][k4+1]=kv.y; kbuf[mm][k4+2]=kv.z; kbuf[mm][k4+3]=kv.w;
        *(float4*)&xbuf[mm][k4] = rrX4[ii];
      }
      __syncthreads();
    }
  }
  #pragma unroll
  for (int d=0; d<4; ++d){
    accA[d] += __shfl_xor(accA[d], 16, 32);
    accB[d] += __shfl_xor(accB[d], 16, 32);
  }
  float invA = 1.f / l_runA, invB = 1.f / l_runB;
  #pragma unroll
  for (int d=0; d<4; ++d){ accA[d] *= invA; accB[d] *= invB; }
  if (ml < 16){
    if (nA < N_){
      float4 o4; o4.x = accA[0]; o4.y = accA[1]; o4.z = accA[2]; o4.w = accA[3];
      *(float4*)&Y[(b*N_+nA)*64 + d0] = o4;
    }
    if (nB < N_){
      float4 o4; o4.x = accB[0]; o4.y = accB[1]; o4.z = accB[2]; o4.w = accB[3];
      *(float4*)&Y[(b*N_+nB)*64 + d0] = o4;
    }
  }
}

// ---------------- pass 2 from cached scores (16 rows/block) ----------------
template<int ADD>
__global__ __launch_bounds__(256) void k_attn_p2(
    const float* __restrict__ Pb,
    const float* __restrict__ X,      // zt1
    const float* __restrict__ X0,     // residual base
    const float* __restrict__ Wg, const float* __restrict__ bg,
    float* __restrict__ cur)
{
  __shared__ __align__(16) float pbuf[16][516];
  __shared__ __align__(16) float xbuf[64][64];
  __shared__ __align__(16) float vbuf[16][64];

  int b = blockIdx.y, n0 = blockIdx.x*16;
  int tid = threadIdx.x;
  int nl = tid >> 5, ml = tid & 31;
  int nA = n0 + nl, nB = n0 + nl + 8;
  int mh = (ml >> 4) << 5;
  int d0 = (ml & 15) * 4;
  float4 rrX4[4];
  const float4 f40 = {0.f,0.f,0.f,0.f};
  const float4 fneg = {-1e30f,-1e30f,-1e30f,-1e30f};

  #pragma unroll
  for (int ii = 0; ii < 8; ++ii){
    int fidx = tid + ii*256;              // 2048 f4 = 16 rows x 512
    int r = fidx >> 7, m4 = (fidx & 127)*4;
    int nn = n0 + r;
    float4 v = (nn < N_) ? *(const float4*)&Pb[((long)(b*N_+nn))*512 + m4] : fneg;
    *(float4*)&pbuf[r][m4] = v;           // row stride 516 floats = 2064 B, 16B-aligned
  }
  __syncthreads();
  float lmaxA = -1e30f, lmaxB = -1e30f;
  for (int m = ml; m < 512; m += 32){
    lmaxA = fmaxf(lmaxA, pbuf[nl  ][m]);
    lmaxB = fmaxf(lmaxB, pbuf[nl+8][m]);
  }
  #pragma unroll
  for (int msk=1; msk<32; msk<<=1){
    lmaxA = fmaxf(lmaxA, __shfl_xor(lmaxA, msk, 32));
    lmaxB = fmaxf(lmaxB, __shfl_xor(lmaxB, msk, 32));
  }
  float lsumA = 0.f, lsumB = 0.f;
  for (int m = ml; m < 512; m += 32){
    float pA = expf(pbuf[nl  ][m] - lmaxA);
    float pB = expf(pbuf[nl+8][m] - lmaxB);
    pbuf[nl  ][m] = pA;
    pbuf[nl+8][m] = pB;
    lsumA += pA; lsumB += pB;
  }
  #pragma unroll
  for (int msk=1; msk<32; msk<<=1){
    lsumA += __shfl_xor(lsumA, msk, 32);
    lsumB += __shfl_xor(lsumB, msk, 32);
  }
  float invA = 1.f/lsumA, invB = 1.f/lsumB;
  for (int m = ml; m < 512; m += 32){
    pbuf[nl  ][m] *= invA;
    pbuf[nl+8][m] *= invB;
  }

  #pragma unroll
  for (int ii=0; ii<4; ++ii){
    int fidx = tid + ii*256;
    int mm = fidx >> 4, k4 = (fidx & 15)*4;
    *(float4*)&xbuf[mm][k4] = *(const float4*)&X[(b*N_+mm)*64+k4];
  }
  __syncthreads();

  float accA[4] = {0.f,0.f,0.f,0.f};
  float accB[4] = {0.f,0.f,0.f,0.f};
  for (int ci = 0; ci < 8; ++ci){
    int m0 = ci*64;
    if (ci < 7){
      #pragma unroll
      for (int ii=0; ii<4; ++ii){
        int fidx = tid + ii*256;
        int mm = fidx >> 4, k4 = (fidx & 15)*4;
        int m = m0+64+mm;
        rrX4[ii] = (m < N_) ? *(const float4*)&X[(b*N_+m)*64+k4] : f40;
      }
    }
    #pragma unroll
    for (int mm = 0; mm < 32; mm += 4){
      float4 pA = *(const float4*)&pbuf[nl  ][m0 + mh + mm];
      float4 pB = *(const float4*)&pbuf[nl+8][m0 + mh + mm];
      float4 x0 = *(const float4*)&xbuf[mh+mm+0][d0];
      float4 x1 = *(const float4*)&xbuf[mh+mm+1][d0];
      float4 x2 = *(const float4*)&xbuf[mh+mm+2][d0];
      float4 x3 = *(const float4*)&xbuf[mh+mm+3][d0];
      accA[0] += pA.x*x0.x + pA.y*x1.x + pA.z*x2.x + pA.w*x3.x;
      accA[1] += pA.x*x0.y + pA.y*x1.y + pA.z*x2.y + pA.w*x3.y;
      accA[2] += pA.x*x0.z + pA.y*x1.z + pA.z*x2.z + pA.w*x3.z;
      accA[3] += pA.x*x0.w + pA.y*x1.w + pA.z*x2.w + pA.w*x3.w;
      accB[0] += pB.x*x0.x + pB.y*x1.x + pB.z*x2.x + pB.w*x3.x;
      accB[1] += pB.x*x0.y + pB.y*x1.y + pB.z*x2.y + pB.w*x3.y;
      accB[2] += pB.x*x0.z + pB.y*x1.z + pB.z*x2.z + pB.w*x3.z;
      accB[3] += pB.x*x0.w + pB.y*x1.w + pB.z*x2.w + pB.w*x3.w;
    }
    __syncthreads();
    if (ci < 7){
      #pragma unroll
      for (int ii=0; ii<4; ++ii){
        int fidx = tid + ii*256;
        int mm = fidx >> 4, k4 = (fidx & 15)*4;
        *(float4*)&xbuf[mm][k4] = rrX4[ii];
      }
      __syncthreads();
    }
  }
  #pragma unroll
  for (int d=0; d<4; ++d){
    accA[d] += __shfl_xor(accA[d], 16, 32);
    accB[d] += __shfl_xor(accB[d], 16, 32);
  }

  {
    if (ml < 16){
      float4 svA = {0.f,0.f,0.f,0.f}, svB = {0.f,0.f,0.f,0.f};
      if (nA < N_){
        int row = b*N_ + nA;
        float4 x0v = *(const float4*)&X0[row*64 + d0];
        float4 z1v = *(const float4*)&X[row*64 + d0];
        svA.x = accA[0] + x0v.x + z1v.x;
        svA.y = accA[1] + x0v.y + z1v.y;
        svA.z = accA[2] + x0v.z + z1v.z;
        svA.w = accA[3] + x0v.w + z1v.w;
      }
      if (nB < N_){
        int row = b*N_ + nB;
        float4 x0v = *(const float4*)&X0[row*64 + d0];
        float4 z1v = *(const float4*)&X[row*64 + d0];
        svB.x = accB[0] + x0v.x + z1v.x;
        svB.y = accB[1] + x0v.y + z1v.y;
        svB.z = accB[2] + x0v.z + z1v.z;
        svB.w = accB[3] + x0v.w + z1v.w;
      }
      *(float4*)&vbuf[nl  ][d0] = svA;
      *(float4*)&vbuf[nl+8][d0] = svB;
    }
    #pragma unroll
    for (int ii=0; ii<4; ++ii){
      int fidx = tid + ii*256;
      int r = fidx >> 4, k4 = (fidx & 15)*4;
      *(float4*)&xbuf[r][k4] = *(const float4*)&Wg[r*64 + k4];
    }
    __syncthreads();
    float oxA = 0.f, oyA = 0.f, oxB = 0.f, oyB = 0.f;
    for (int kk = 0; kk < 64; ++kk){
      float sA = vbuf[nl][kk], sB = vbuf[nl+8][kk];
      float2 w2 = *(const float2*)&xbuf[kk][ml*2];
      oxA += sA*w2.x; oyA += sA*w2.y;
      oxB += sB*w2.x; oyB += sB*w2.y;
    }
    float2 bv = *(const float2*)&bg[ml*2];
    if (nA < N_){
      int row = b*N_ + nA;
      float vx = oxA + bv.x, vy = oyA + bv.y;
      if (ADD){
        float2 old = *(const float2*)&cur[row*64 + ml*2];
        vx += old.x; vy += old.y;
      }
      float2 o2; o2.x = vx; o2.y = vy;
      *(float2*)&cur[row*64 + ml*2] = o2;
    }
    if (nB < N_){
      int row = b*N_ + nB;
      float vx = oxB + bv.x, vy = oyB + bv.y;
      if (ADD){
        float2 old = *(const float2*)&cur[row*64 + ml*2];
        vx += old.x; vy += old.y;
      }
      float2 o2; o2.x = vx; o2.y = vy;
      *(float2*)&cur[row*64 + ml*2] = o2;
    }
  }
}

// ---------------- output head (R5: 8 rows/block, halves W1 L2 re-reads) ------
__global__ __launch_bounds__(128) void k_out(const float* __restrict__ cur,
                                             const float* __restrict__ W1, const float* __restrict__ bb1,
                                             const float* __restrict__ W2, const float* __restrict__ bb2,
                                             float* __restrict__ out){
  __shared__ float ch[8][64];
  __shared__ float hid[8*1200];
  int tid = threadIdx.x;
  int rbase = blockIdx.x*8;
  for (int idx = tid; idx < 512; idx += 128){
    int r = idx >> 6, h = idx & 63;
    ch[r][h] = cur[(rbase+r)*64 + h];
  }
  __syncthreads();
  for (int job = tid; job < 1200; job += 128){
    int t = job / 100, f = job - t*100;
    float bb = bb1[t*100+f];
    float a0=bb,a1=bb,a2=bb,a3=bb,a4=bb,a5=bb,a6=bb,a7=bb;
    for (int h = 0; h < 64; ++h){
      float w = W1[(t*64+h)*100 + f];
      a0 += ch[0][h]*w; a1 += ch[1][h]*w; a2 += ch[2][h]*w; a3 += ch[3][h]*w;
      a4 += ch[4][h]*w; a5 += ch[5][h]*w; a6 += ch[6][h]*w; a7 += ch[7][h]*w;
    }
    hid[0*1200+job] = (a0 > 0.f) ? a0 : expm1f(a0);
    hid[1*1200+job] = (a1 > 0.f) ? a1 : expm1f(a1);
    hid[2*1200+job] = (a2 > 0.f) ? a2 : expm1f(a2);
    hid[3*1200+job] = (a3 > 0.f) ? a3 : expm1f(a3);
    hid[4*1200+job] = (a4 > 0.f) ? a4 : expm1f(a4);
    hid[5*1200+job] = (a5 > 0.f) ? a5 : expm1f(a5);
    hid[6*1200+job] = (a6 > 0.f) ? a6 : expm1f(a6);
    hid[7*1200+job] = (a7 > 0.f) ? a7 : expm1f(a7);
  }
  __syncthreads();
  for (int jb = tid; jb < 192; jb += 128){
    int r = jb / 24, rem = jb % 24;
    int t = rem >> 1, o = rem & 1;
    float a = bb2[t*2+o];
    const float* hp = hid + r*1200 + t*100;
    for (int f = 0; f < 100; ++f) a += hp[f] * W2[(t*100+f)*2+o];
    out[(rbase+r)*24 + t*2+o] = a;
  }
}

// ---------------- launch ----------------
extern "C" void kernel_launch(void* const* d_in, const int* in_sizes, int n_in,
                              void* d_out, int out_size, void* d_ws, size_t ws_size,
                              hipStream_t stream)
{
  const float* x        = (const float*)d_in[0];
  const float* geo      = (const float*)d_in[2];
  const float* fcx_W    = (const float*)d_in[3];
  const float* fcx_b    = (const float*)d_in[4];
  const float* env_cb   = (const float*)d_in[5];
  const float* nodes_cb = (const float*)d_in[6];
  const float* w_v      = (const float*)d_in[7];
  const float* w_k      = (const float*)d_in[8];
  const float* w_q      = (const float*)d_in[9];
  const float* core_W   = (const float*)d_in[10];
  const float* core_b   = (const float*)d_in[11];
  const float* tN_Win   = (const float*)d_in[12];
  const float* tN_bin   = (const float*)d_in[13];
  const float* tN_Wf    = (const float*)d_in[14];
  const float* tN_bf    = (const float*)d_in[15];
  const float* tN_Wg    = (const float*)d_in[16];
  const float* tN_bg    = (const float*)d_in[17];
  const float* tN_Wout  = (const float*)d_in[18];
  const float* tN_bout  = (const float*)d_in[19];
  const float* tP_Win   = (const float*)d_in[20];
  const float* tP_bin   = (const float*)d_in[21];
  const float* tP_Wf    = (const float*)d_in[22];
  const float* tP_bf    = (const float*)d_in[23];
  const float* tP_Wg    = (const float*)d_in[24];
  const float* tP_bg    = (const float*)d_in[25];
  const float* tP_Wout  = (const float*)d_in[26];
  const float* tP_bout  = (const float*)d_in[27];
  const float* bn1_g    = (const float*)d_in[28];
  const float* bn1_b    = (const float*)d_in[29];
  const float* bnP_g    = (const float*)d_in[30];
  const float* bnP_b    = (const float*)d_in[31];
  const float* gcn1_W   = (const float*)d_in[32];
  const float* gcn1_b   = (const float*)d_in[33];
  const float* gcn2_W   = (const float*)d_in[34];
  const float* gcn2_b   = (const float*)d_in[35];
  const float* gcnp_W   = (const float*)d_in[36];
  const float* gcnp_b   = (const float*)d_in[37];
  const float* nv_p1    = (const float*)d_in[38];
  const float* nv_p2    = (const float*)d_in[39];
  const float* nv_p3    = (const float*)d_in[40];
  const float* nv_pk    = (const float*)d_in[41];
  const float* out_W1   = (const float*)d_in[42];
  const float* out_b1   = (const float*)d_in[43];
  const float* out_W2   = (const float*)d_in[44];
  const float* out_b2   = (const float*)d_in[45];
  const int*   t_pos    = (const int*)d_in[46];
  const int*   ind      = (const int*)d_in[47];

  // Base: 4096 B + 2,223,616 floats. Pb: +4,096,000 floats (gate 25.28 MB).
  // TE (212,480 floats) ALIASES Pb's start: consumed by k_tcn2 before p1 writes Pb.
  // Gsum (250,000 floats) ALIASES zt1: consumed by fused gcn1 before gcn2's p1
  // writes zt1. Header: node_list[512], off[16], chunkOff[21] ints < 4096 B.
  int* node_list = (int*)d_ws;
  int* off       = node_list + 512;
  float* F = (float*)((char*)d_ws + 4096);
  float* temb   = F + 0;
  float* core_f = F + 12288;
  float* tmp1   = F + 77824;
  float* stats  = F + 143360;
  float* matq   = F + 143616;
  float* unb    = F + 175616;
  float* hpr    = F + 687616;
  float* cur    = F + 1199616;
  float* zt1    = F + 1711616;
  float* Pb     = F + 2223616;
  float* TE     = Pb;            // alias (disjoint lifetimes)
  float* Gsum   = zt1;           // alias (dead before gcn2 p1 writes zt1)
  bool useP = ws_size >= (size_t)(4096 + (size_t)(2223616 + 4096000)*4);

  k_matq <<<dim3(125), dim3(256), 0, stream>>>(nodes_cb, w_q, matq);
  k_route<<<dim3(1),   dim3(256), 0, stream>>>(env_cb, w_v, w_k, matq, node_list, off);
  k_temb <<<dim3(1),   dim3(192), 0, stream>>>(t_pos, temb);
  k_core <<<dim3(256), dim3(256), 0, stream>>>(temb, core_W, core_b, core_f);
  if (useP){
    k_tprep<<<dim3(20, 81), dim3(128), 0, stream>>>(temb, fcx_W, fcx_b, tN_Win, tP_Win, TE);
    k_tcn2 <<<dim3(NTCN2), dim3(256), 0, stream>>>(x, TE, node_list, off,
        tN_bin, tN_Wf, tN_bf, tN_Wg, tN_bg, tN_Wout, tN_bout,
        tP_bin, tP_Wf, tP_bf, tP_Wg, tP_bg, tP_Wout, tP_bout,
        unb, hpr);
    k_geo2 <<<dim3(125), dim3(256), 0, stream>>>(geo, Gsum);
  } else {
    k_tcn  <<<dim3(20, 334), dim3(256), 0, stream>>>(x, fcx_W, fcx_b, temb, node_list, off,
        tN_Win, tN_bin, tN_Wf, tN_bf, tN_Wg, tN_bg, tN_Wout, tN_bout,
        tP_Win, tP_bin, tP_Wf, tP_bf, tP_Wg, tP_bg, tP_Wout, tP_bout,
        unb, hpr);
  }
  k_bnstats<<<dim3(128), dim3(256), 0, stream>>>(unb, hpr, stats);
  k_bnapply<<<dim3(1000),dim3(256), 0, stream>>>(unb, hpr, stats, bn1_g, bn1_b, bnP_g, bnP_b);
  k_tmp1<<<dim3(256), dim3(256), 0, stream>>>(ind, nv_p1, nv_pk, tmp1);

  dim3 ag(32, 16);
  const float* nil = nullptr;
  // gcn1: geo adjacency on h_prev
  if (useP){
    // fused: cur = (hpr + (geo+geo^2)@hpr) @ W1 + b1   (one pass, no Z1)
    k_attn<0,0,2,0><<<ag, 256, 0, stream>>>(Gsum, nil,nil,nil, nil,nil,
                                   hpr, hpr, nil, gcn1_W, gcn1_b, cur, nullptr);
  } else {
    k_attn<0,0,0,0><<<ag, 256, 0, stream>>>(geo, nil,nil,nil, nil,nil,
                                   hpr, nil,nil, nil,nil, nullptr, zt1);
    k_attn<0,0,1,0><<<ag, 256, 0, stream>>>(geo, nil,nil,nil, nil,nil,
                                   zt1, hpr, zt1, gcn1_W, gcn1_b, cur, nullptr);
  }
  // gcn2: causal adjacency on unbias
  if (useP){
    k_attn_p1<1,0><<<ag, 256, 0, stream>>>(unb, nil, core_f, hpr, nil, unb, Pb, zt1);
    k_attn_p2<1>  <<<ag, 256, 0, stream>>>(Pb, zt1, unb, gcn2_W, gcn2_b, cur);
  } else {
    k_attn<1,0,0,0><<<ag, 256, 0, stream>>>(nil, unb,nil, core_f, hpr,nil,
                                   unb, nil,nil, nil,nil, nullptr, zt1);
    k_attn<1,0,1,1><<<ag, 256, 0, stream>>>(nil, unb,nil, core_f, hpr,nil,
                                   zt1, unb, zt1, gcn2_W, gcn2_b, cur, nullptr);
  }
  // gcnp: adaptive adjacency on unbias
  if (useP){
    k_attn_p1<2,1><<<ag, 256, 0, stream>>>(nil, nv_p2, tmp1, nil, nv_p3, unb, Pb, zt1);
    k_attn_p2<1>  <<<ag, 256, 0, stream>>>(Pb, zt1, unb, gcnp_W, gcnp_b, cur);
  } else {
    k_attn<2,1,0,0><<<ag, 256, 0, stream>>>(nil, nil,nv_p2, tmp1, nil,nv_p3,
                                   unb, nil,nil, nil,nil, nullptr, zt1);
    k_attn<2,1,1,1><<<ag, 256, 0, stream>>>(nil, nil,nv_p2, tmp1, nil,nv_p3,
                                   zt1, unb, zt1, gcnp_W, gcnp_b, cur, nullptr);
  }
  // head
  k_out<<<dim3(1000), dim3(128), 0, stream>>>(cur, out_W1, out_b1, out_W2, out_b2, (float*)d_out);
}

// Round 12
// 831.239 us; speedup vs baseline: 1.0930x; 1.0930x over previous
//
#include <hip/hip_runtime.h>
#include <hip/hip_bf16.h>
#include <math.h>

#define B_ 16
#define N_ 500
#define T_ 12
#define K_ 10
#define NROWS (B_*N_)   // 8000
#define TROWS 6         // rows per work chunk
#define NTCN2 2688      // fixed grid for k_tcn2 (>= max compact chunks 2686)

// ---------------- threefry / gumbel (jax.random.key(42)) ----------------
__device__ __forceinline__ unsigned rotl32(unsigned v, int r){ return (v<<r)|(v>>(32-r)); }

__device__ __forceinline__ void threefry2x32(unsigned k0, unsigned k1,
                                             unsigned c0, unsigned c1,
                                             unsigned &o0, unsigned &o1){
  unsigned ks2 = k0 ^ k1 ^ 0x1BD11BDAu;
  unsigned x0 = c0 + k0, x1 = c1 + k1;
#define TF_R(r) { x0 += x1; x1 = rotl32(x1,(r)); x1 ^= x0; }
  TF_R(13) TF_R(15) TF_R(26) TF_R(6)
  x0 += k1;  x1 += ks2 + 1u;
  TF_R(17) TF_R(29) TF_R(16) TF_R(24)
  x0 += ks2; x1 += k0 + 2u;
  TF_R(13) TF_R(15) TF_R(26) TF_R(6)
  x0 += k0;  x1 += k1 + 3u;
  TF_R(17) TF_R(29) TF_R(16) TF_R(24)
  x0 += k1;  x1 += ks2 + 4u;
  TF_R(13) TF_R(15) TF_R(26) TF_R(6)
  x0 += ks2; x1 += k0 + 5u;
#undef TF_R
  o0 = x0; o1 = x1;
}

// Partitionable threefry (JAX >= 0.4.30): bits[i] = x0 ^ x1 of threefry(key,(0,i)).
// VERIFIED bit-exact vs harness (round 5 pass).
__device__ __forceinline__ float gumbel_at(unsigned idx){
  unsigned b0, b1;
  threefry2x32(0u, 42u, 0u, idx, b0, b1);
  unsigned bits = b0 ^ b1;
  float u = __uint_as_float((bits >> 9) | 0x3f800000u) - 1.0f;  // [0,1)
  u = fmaxf(u, 1.17549435e-38f);
  return -logf(-logf(u));
}

// ---------------- matq = nodes_cb @ w_q ----------------
__global__ __launch_bounds__(256) void k_matq(const float* __restrict__ nodes_cb,
                                              const float* __restrict__ w_q,
                                              float* __restrict__ matq){
  int idx = blockIdx.x*256 + threadIdx.x;
  if (idx >= N_*64) return;
  int n = idx >> 6, d = idx & 63;
  float a = 0.f;
  for (int c = 0; c < 64; ++c) a += nodes_cb[n*64+c] * w_q[c*64+d];
  matq[idx] = a;
}

// ---------------- routing ----------------
// Also emits compact chunk prefix sums at off+16: chunkOff[s] for slot s in
// [0,20], chunkOff[20] = nwork (sum of ceil(cnt*16/TROWS) over 20 slots).
__global__ __launch_bounds__(256) void k_route(const float* __restrict__ env_cb,
                                               const float* __restrict__ w_v,
                                               const float* __restrict__ w_k,
                                               const float* __restrict__ matq,
                                               int* __restrict__ node_list,
                                               int* __restrict__ off){
  __shared__ float smk[K_*64];
  __shared__ float smv[K_*K_];
  __shared__ int sroute[N_];
  int tid = threadIdx.x;
  for (int idx = tid; idx < K_*64; idx += 256){
    int kk = idx >> 6, d = idx & 63;
    float a = 0.f;
    for (int c = 0; c < 64; ++c) a += env_cb[kk*64+c] * w_k[c*64+d];
    smk[idx] = a;
  }
  for (int idx = tid; idx < K_*K_; idx += 256){
    int kk = idx / K_, j = idx % K_;
    float a = 0.f;
    for (int c = 0; c < 64; ++c) a += env_cb[kk*64+c] * w_v[c*K_+j];
    smv[idx] = a;
  }
  __syncthreads();
  for (int n = tid; n < N_; n += 256){
    float s[K_];
    float mx = -1e30f;
    for (int j = 0; j < K_; ++j){
      float a = 0.f;
      for (int d = 0; d < 64; ++d) a += matq[n*64+d]*smk[j*64+d];
      s[j] = a * 0.125f;
      mx = fmaxf(mx, s[j]);
    }
    float sum = 0.f;
    for (int j = 0; j < K_; ++j){ s[j] = expf(s[j]-mx); sum += s[j]; }
    float inv = 1.f/sum;
    int best = 0; float bestv = -1e30f;
    for (int j2 = 0; j2 < K_; ++j2){
      float lg = 0.f;
      for (int j = 0; j < K_; ++j) lg += s[j]*inv*smv[j*K_+j2];
      float tot = lg + gumbel_at((unsigned)(n*K_+j2));
      if (tot > bestv){ bestv = tot; best = j2; }
    }
    sroute[n] = best;
  }
  __syncthreads();
  if (tid == 0){
    int cnt[K_]; for (int j=0;j<K_;++j) cnt[j]=0;
    for (int n=0;n<N_;++n) cnt[sroute[n]]++;
    int acc=0;
    for (int j=0;j<K_;++j){ off[j]=acc; acc+=cnt[j]; }
    off[K_]=acc;
    int pos[K_]; for (int j=0;j<K_;++j) pos[j]=off[j];
    for (int n=0;n<N_;++n) node_list[pos[sroute[n]]++] = n;
    // compact work-chunk prefix sums (slot-major, both paths of expert k adjacent)
    int* chunkOff = off + 16;
    int ck = 0;
    chunkOff[0] = 0;
    for (int s = 0; s < 2*K_; ++s){
      int rows = cnt[s >> 1] * 16;
      ck += (rows + TROWS - 1) / TROWS;
      chunkOff[s+1] = ck;
    }
  }
}

// ---------------- t_emb ----------------
__global__ void k_temb(const int* __restrict__ t_pos, float* __restrict__ temb){
  int tid = threadIdx.x;
  if (tid >= B_*T_) return;
  int b = tid / T_, t = tid % T_;
  int p0 = t_pos[(b*T_+t)*2+0], p1 = t_pos[(b*T_+t)*2+1];
  float tp = (float)((p0 <= 4) ? p1 : 23 + p1);
  float c0 = -logf(10000.f)/32.f;
  for (int j = 0; j < 32; ++j){
    float a = tp * expf(c0 * (float)j);
    temb[(b*T_+t)*64 + j]      = cosf(a);
    temb[(b*T_+t)*64 + 32 + j] = sinf(a);
  }
}

// ---------------- core[b] ----------------
__global__ __launch_bounds__(256) void k_core(const float* __restrict__ temb,
                                              const float* __restrict__ core_W,
                                              const float* __restrict__ core_b,
                                              float* __restrict__ core_f){
  int idx = blockIdx.x*256 + threadIdx.x;
  if (idx >= B_*4096) return;
  int b = idx >> 12, c = idx & 4095;
  const float* te = temb + (b*T_ + 11)*64;
  float a = core_b[c];
  for (int h = 0; h < 64; ++h) a += te[h] * core_W[h*4096 + c];
  core_f[idx] = a;
}

// ---------------- tmp1[b] ----------------
__global__ __launch_bounds__(256) void k_tmp1(const int* __restrict__ ind,
                                              const float* __restrict__ nv_p1,
                                              const float* __restrict__ nv_pk,
                                              float* __restrict__ tmp1){
  int idx = blockIdx.x*256 + threadIdx.x;
  if (idx >= B_*4096) return;
  int b = idx >> 12, c = idx & 4095;
  int i0 = ind[(b*T_+1)*2+0], i1 = ind[(b*T_+1)*2+1];
  int row = (i0 <= 4) ? i1 : 23 + i1;
  const float* te = nv_p1 + row*64;
  float a = 0.f;
  for (int h = 0; h < 64; ++h) a += te[h] * nv_pk[h*4096 + c];
  tmp1[idx] = a;
}

// ---------------- TCN stage-1 precompute (PARALLEL: grid (20,81) x 128) ----------------
__global__ __launch_bounds__(128) void k_tprep(
    const float* __restrict__ temb,
    const float* __restrict__ fcx_W, const float* __restrict__ fcx_b,
    const float* __restrict__ WinN, const float* __restrict__ WinP,
    float* __restrict__ TE)
{
  int slot = blockIdx.x;
  int y = blockIdx.y;
  int k = slot >> 1, path = slot & 1;
  const float* Win = (path ? WinP : WinN) + k*16384;
  int o = threadIdx.x;
  if (y < 80){
    __shared__ float ste[64];
    int b = y/5, t = y%5;
    if (o < 64) ste[o] = temb[(b*T_ + t)*64 + o];
    __syncthreads();
    float acc = 0.f;
    for (int cc = 0; cc < 64; ++cc) acc += ste[cc] * Win[(64+cc)*128 + o];
    TE[slot*10240 + y*128 + o] = acc;
  } else {
    float a0=0.f, a1=0.f, c0=0.f;
    for (int c = 0; c < 64; ++c){
      float w = Win[c*128 + o];
      a0 += fcx_W[c]*w; a1 += fcx_W[64+c]*w; c0 += fcx_b[c]*w;
    }
    float* AAs = TE + 20*10240 + slot*384;
    AAs[o] = a0; AAs[128+o] = a1; AAs[256+o] = c0;
  }
}

// ---------------- TCN v4 (R4 WINNER, unchanged): compact list + balanced XCD --
// Verified R4/R6/R10: dur ~196us, VALUBusy 76-78%, FETCH 8.8MB. Issue-mix-bound
// (96 FMA / 124 insts = 77% ~ measured VALUBusy). Final configuration.
__global__ __launch_bounds__(256) void k_tcn2(
    const float* __restrict__ x,
    const float* __restrict__ TE,
    const int* __restrict__ node_list, const int* __restrict__ off,
    const float* __restrict__ binN,
    const float* __restrict__ WfN,  const float* __restrict__ bfN,
    const float* __restrict__ WgN,  const float* __restrict__ bgN,
    const float* __restrict__ WoutN,const float* __restrict__ boutN,
    const float* __restrict__ binP,
    const float* __restrict__ WfP,  const float* __restrict__ bfP,
    const float* __restrict__ WgP,  const float* __restrict__ bgP,
    const float* __restrict__ WoutP,const float* __restrict__ boutP,
    float* __restrict__ out_unb, float* __restrict__ out_hpr)
{
  const int* chunkOff = off + 16;
  int nwork = chunkOff[2*K_];
  int q = (nwork + 7) >> 3;
  int id = blockIdx.x;
  int xcd = id & 7, pos = id >> 3;
  if (pos >= q) return;
  int w = xcd*q + pos;
  if (w >= nwork) return;
  int slot = 0;
  #pragma unroll 1
  while (chunkOff[slot+1] <= w) ++slot;
  int r0 = (w - chunkOff[slot]) * TROWS;

  int k = slot >> 1;
  int path = slot & 1;
  int cnt = off[k+1] - off[k];
  int rows = cnt * 16;
  if (r0 >= rows) return;

  const float* bin  = (path ? binP  : binN)  + k*128;
  const float* Wf   = (path ? WfP   : WfN)   + k*4*16384;
  const float* bf_  = (path ? bfP   : bfN)   + k*2*128;
  const float* Wg   = (path ? WgP   : WgN)   + k*4*16384;
  const float* bg_  = (path ? bgP   : bgN)   + k*2*128;
  const float* Wout = (path ? WoutP : WoutN) + k*8192;
  const float* bout = (path ? boutP : boutN) + k*64;
  float* outb = path ? out_hpr : out_unb;
  int t0 = path ? 0 : 1;

  __shared__ __align__(16) float sH0[TROWS*512];
  __shared__ __align__(16) float sH1[TROWS*256];
  __shared__ __align__(16) float sH2[TROWS*128];
  __shared__ float xs[TROWS][4][2];
  __shared__ int rowBN[TROWS];
  __shared__ int rowB[TROWS];

  int tid = threadIdx.x;
  if (tid < TROWS){
    int r = r0 + tid;
    if (r < rows){
      int node = node_list[off[k] + (r >> 4)];
      int b = r & 15;
      rowBN[tid] = b*N_ + node;
      rowB[tid]  = b;
    } else { rowBN[tid] = -1; rowB[tid] = 0; }
  }
  __syncthreads();
  if (tid < TROWS*4){
    int i = tid >> 2, tl = tid & 3;
    int rb = rowBN[i];
    float x0 = 0.f, x1 = 0.f;
    if (rb >= 0){
      const float* xp = x + (rb*T_ + tl + t0)*2;
      x0 = xp[0]; x1 = xp[1];
    }
    xs[i][tl][0] = x0; xs[i][tl][1] = x1;
  }
  __syncthreads();

  // Stage 1 (algebraic): h0 = x0*A0 + x1*A1 + C0 + TE[b][tl+t0] + bin
  {
    int o = tid & 127, half = tid >> 7;
    const float* AAs = TE + 20*10240 + slot*384;
    const float* TEs = TE + slot*10240;
    float a0 = AAs[o], a1 = AAs[128+o], c0 = AAs[256+o];
    float bn = bin[o];
    #pragma unroll
    for (int jj = 0; jj < 12; ++jj){
      int rt = half*12 + jj;
      int i = rt >> 2, tl = rt & 3;
      float v = xs[i][tl][0]*a0 + xs[i][tl][1]*a1 + c0
              + TEs[(rowB[i]*5 + tl + t0)*128 + o] + bn;
      sH0[rt*128 + o] = v;
    }
  }
  __syncthreads();

  // Stage 2: block0 (d=1), fused f+g, sH0 -> sH1.
  {
    int o = tid & 127;
    int jg = (tid >> 7)*6;
    float af[6], ag[6];
    #pragma unroll
    for (int j=0;j<6;++j){ af[j]=0.f; ag[j]=0.f; }
    for (int c = 0; c < 128; c += 4){
      float f00=Wf[(c+0)*128+o], f01=Wf[(c+1)*128+o], f02=Wf[(c+2)*128+o], f03=Wf[(c+3)*128+o];
      float f10=Wf[16384+(c+0)*128+o], f11=Wf[16384+(c+1)*128+o], f12=Wf[16384+(c+2)*128+o], f13=Wf[16384+(c+3)*128+o];
      float g00=Wg[(c+0)*128+o], g01=Wg[(c+1)*128+o], g02=Wg[(c+2)*128+o], g03=Wg[(c+3)*128+o];
      float g10=Wg[16384+(c+0)*128+o], g11=Wg[16384+(c+1)*128+o], g12=Wg[16384+(c+2)*128+o], g13=Wg[16384+(c+3)*128+o];
      #pragma unroll
      for (int jj=0;jj<6;++jj){
        int j = jg + jj;
        int i = j >> 1, ti = j & 1;
        float4 xa = *(const float4*)&sH0[(i*4+ti*2  )*128 + c];
        float4 xb = *(const float4*)&sH0[(i*4+ti*2+1)*128 + c];
        af[jj] += xa.x*f00 + xa.y*f01 + xa.z*f02 + xa.w*f03
                + xb.x*f10 + xb.y*f11 + xb.z*f12 + xb.w*f13;
        ag[jj] += xa.x*g00 + xa.y*g01 + xa.z*g02 + xa.w*g03
                + xb.x*g10 + xb.y*g11 + xb.z*g12 + xb.w*g13;
      }
    }
    float bfv = bf_[o], bgv = bg_[o];
    #pragma unroll
    for (int jj=0;jj<6;++jj){
      int j = jg + jj;
      int i = j >> 1, ti = j & 1;
      float f = tanhf(af[jj] + bfv);
      float g = 1.f/(1.f + expf(-(ag[jj] + bgv)));
      sH1[j*128 + o] = f*g + sH0[(i*4 + ti*2 + 1)*128 + o];
    }
  }
  __syncthreads();

  // Stage 3: block1 (d=2), fused f+g, sH1 -> sH2.
  {
    int o = tid & 127;
    int ig = (tid >> 7)*3;
    const float* Wf1 = Wf + 2*16384;
    const float* Wg1 = Wg + 2*16384;
    float af[3], ag[3];
    #pragma unroll
    for (int i=0;i<3;++i){ af[i]=0.f; ag[i]=0.f; }
    for (int c = 0; c < 128; c += 4){
      float f00=Wf1[(c+0)*128+o], f01=Wf1[(c+1)*128+o], f02=Wf1[(c+2)*128+o], f03=Wf1[(c+3)*128+o];
      float f10=Wf1[16384+(c+0)*128+o], f11=Wf1[16384+(c+1)*128+o], f12=Wf1[16384+(c+2)*128+o], f13=Wf1[16384+(c+3)*128+o];
      float g00=Wg1[(c+0)*128+o], g01=Wg1[(c+1)*128+o], g02=Wg1[(c+2)*128+o], g03=Wg1[(c+3)*128+o];
      float g10=Wg1[16384+(c+0)*128+o], g11=Wg1[16384+(c+1)*128+o], g12=Wg1[16384+(c+2)*128+o], g13=Wg1[16384+(c+3)*128+o];
      #pragma unroll
      for (int ii=0;ii<3;++ii){
        int i = ig + ii;
        float4 xa = *(const float4*)&sH1[(i*2+0)*128 + c];
        float4 xb = *(const float4*)&sH1[(i*2+1)*128 + c];
        af[ii] += xa.x*f00 + xa.y*f01 + xa.z*f02 + xa.w*f03
                + xb.x*f10 + xb.y*f11 + xb.z*f12 + xb.w*f13;
        ag[ii] += xa.x*g00 + xa.y*g01 + xa.z*g02 + xa.w*g03
                + xb.x*g10 + xb.y*g11 + xb.z*g12 + xb.w*g13;
      }
    }
    float bfv = bf_[128+o], bgv = bg_[128+o];
    #pragma unroll
    for (int ii=0;ii<3;++ii){
      int i = ig + ii;
      float f = tanhf(af[ii] + bfv);
      float g = 1.f/(1.f + expf(-(ag[ii] + bgv)));
      sH2[i*128 + o] = f*g + sH1[(i*2+1)*128 + o];
    }
  }
  __syncthreads();

  // Stage 4: out = h2 @ Wout + bout (128 -> 64)
  {
    int o6 = tid & 63, grp = tid >> 6;
    #pragma unroll
    for (int ii=0; ii<2; ++ii){
      int i = grp*2 + ii;
      if (i >= TROWS) continue;
      float acc = 0.f;
      for (int c = 0; c < 128; c += 4){
        float w0=Wout[(c+0)*64+o6], w1=Wout[(c+1)*64+o6],
              w2=Wout[(c+2)*64+o6], w3=Wout[(c+3)*64+o6];
        float4 xv = *(const float4*)&sH2[i*128 + c];
        acc += xv.x*w0 + xv.y*w1 + xv.z*w2 + xv.w*w3;
      }
      if (rowBN[i] >= 0) outb[rowBN[i]*64 + o6] = acc + bout[o6];
    }
  }
}

// ---------------- fused per-expert TCN (fallback when !useP) ----------------
__global__ __launch_bounds__(256) void k_tcn(
    const float* __restrict__ x,
    const float* __restrict__ fcx_W, const float* __restrict__ fcx_b,
    const float* __restrict__ temb,
    const int* __restrict__ node_list, const int* __restrict__ off,
    const float* __restrict__ WinN, const float* __restrict__ binN,
    const float* __restrict__ WfN,  const float* __restrict__ bfN,
    const float* __restrict__ WgN,  const float* __restrict__ bgN,
    const float* __restrict__ WoutN,const float* __restrict__ boutN,
    const float* __restrict__ WinP, const float* __restrict__ binP,
    const float* __restrict__ WfP,  const float* __restrict__ bfP,
    const float* __restrict__ WgP,  const float* __restrict__ bgP,
    const float* __restrict__ WoutP,const float* __restrict__ boutP,
    float* __restrict__ out_unb, float* __restrict__ out_hpr)
{
  int slot = blockIdx.x;
  int k = slot >> 1;
  int path = slot & 1;
  int cnt = off[k+1] - off[k];
  int rows = cnt * 16;
  int r0 = blockIdx.y * TROWS;
  if (r0 >= rows) return;

  const float* Win  = (path ? WinP  : WinN)  + k*16384;
  const float* bin  = (path ? binP  : binN)  + k*128;
  const float* Wf   = (path ? WfP   : WfN)   + k*4*16384;
  const float* bf_  = (path ? bfP   : bfN)   + k*2*128;
  const float* Wg   = (path ? WgP   : WgN)   + k*4*16384;
  const float* bg_  = (path ? bgP   : bgN)   + k*2*128;
  const float* Wout = (path ? WoutP : WoutN) + k*8192;
  const float* bout = (path ? boutP : boutN) + k*64;
  float* outb = path ? out_hpr : out_unb;
  int t0 = path ? 0 : 1;

  __shared__ __align__(16) float sIn[TROWS*512];
  __shared__ __align__(16) float sH0[TROWS*512];
  __shared__ __align__(16) float sH1[TROWS*256];
  __shared__ __align__(16) float sH2[TROWS*128];
  __shared__ int rowBN[TROWS];
  __shared__ int rowB[TROWS];

  int tid = threadIdx.x;
  if (tid < TROWS){
    int r = r0 + tid;
    if (r < rows){
      int node = node_list[off[k] + (r >> 4)];
      int b = r & 15;
      rowBN[tid] = b*N_ + node;
      rowB[tid]  = b;
    } else { rowBN[tid] = -1; rowB[tid] = 0; }
  }
  __syncthreads();

  for (int i = 0; i < TROWS; ++i){
    int rb = rowBN[i], b = rowB[i];
    for (int c2 = tid; c2 < 512; c2 += 256){
      int t = (c2 >> 7) + t0, c = c2 & 127;
      float v = 0.f;
      if (rb >= 0){
        if (c < 64){
          const float* xp = x + (rb*T_ + t)*2;
          v = xp[0]*fcx_W[c] + xp[1]*fcx_W[64+c] + fcx_b[c];
        } else {
          v = temb[(b*T_ + t)*64 + (c-64)];
        }
      }
      sIn[i*512 + c2] = v;
    }
  }
  __syncthreads();

  {
    int oc = (tid & 63)*2;
    int jg = (tid >> 6)*6;
    float a0[6], a1[6];
    #pragma unroll
    for (int j=0;j<6;++j){ a0[j]=0.f; a1[j]=0.f; }
    for (int c = 0; c < 128; c += 4){
      float2 w0 = *(const float2*)(Win + (c+0)*128 + oc);
      float2 w1 = *(const float2*)(Win + (c+1)*128 + oc);
      float2 w2 = *(const float2*)(Win + (c+2)*128 + oc);
      float2 w3 = *(const float2*)(Win + (c+3)*128 + oc);
      #pragma unroll
      for (int j=0;j<6;++j){
        float4 xv = *(const float4*)&sIn[(jg+j)*128 + c];
        a0[j] += xv.x*w0.x + xv.y*w1.x + xv.z*w2.x + xv.w*w3.x;
        a1[j] += xv.x*w0.y + xv.y*w1.y + xv.z*w2.y + xv.w*w3.y;
      }
    }
    float b0v = bin[oc], b1v = bin[oc+1];
    #pragma unroll
    for (int j=0;j<6;++j){
      sH0[(jg+j)*128 + oc]   = a0[j] + b0v;
      sH0[(jg+j)*128 + oc+1] = a1[j] + b1v;
    }
  }
  __syncthreads();

  {
    int o = tid & 127;
    int jg = (tid >> 7)*6;
    float af[6], ag[6];
    #pragma unroll
    for (int j=0;j<6;++j){ af[j]=0.f; ag[j]=0.f; }
    for (int c = 0; c < 128; c += 4){
      float f00=Wf[(c+0)*128+o], f01=Wf[(c+1)*128+o], f02=Wf[(c+2)*128+o], f03=Wf[(c+3)*128+o];
      float f10=Wf[16384+(c+0)*128+o], f11=Wf[16384+(c+1)*128+o], f12=Wf[16384+(c+2)*128+o], f13=Wf[16384+(c+3)*128+o];
      float g00=Wg[(c+0)*128+o], g01=Wg[(c+1)*128+o], g02=Wg[(c+2)*128+o], g03=Wg[(c+3)*128+o];
      float g10=Wg[16384+(c+0)*128+o], g11=Wg[16384+(c+1)*128+o], g12=Wg[16384+(c+2)*128+o], g13=Wg[16384+(c+3)*128+o];
      #pragma unroll
      for (int jj=0;jj<6;++jj){
        int j = jg + jj;
        int i = j >> 1, ti = j & 1;
        float4 xa = *(const float4*)&sH0[(i*4+ti*2  )*128 + c];
        float4 xb = *(const float4*)&sH0[(i*4+ti*2+1)*128 + c];
        af[jj] += xa.x*f00 + xa.y*f01 + xa.z*f02 + xa.w*f03
                + xb.x*f10 + xb.y*f11 + xb.z*f12 + xb.w*f13;
        ag[jj] += xa.x*g00 + xa.y*g01 + xa.z*g02 + xa.w*g03
                + xb.x*g10 + xb.y*g11 + xb.z*g12 + xb.w*g13;
      }
    }
    float bfv = bf_[o], bgv = bg_[o];
    #pragma unroll
    for (int jj=0;jj<6;++jj){
      int j = jg + jj;
      int i = j >> 1, ti = j & 1;
      float f = tanhf(af[jj] + bfv);
      float g = 1.f/(1.f + expf(-(ag[jj] + bgv)));
      sH1[j*128 + o] = f*g + sH0[(i*4 + ti*2 + 1)*128 + o];
    }
  }
  __syncthreads();

  {
    int o = tid & 127;
    int ig = (tid >> 7)*3;
    const float* Wf1 = Wf + 2*16384;
    const float* Wg1 = Wg + 2*16384;
    float af[3], ag[3];
    #pragma unroll
    for (int i=0;i<3;++i){ af[i]=0.f; ag[i]=0.f; }
    for (int c = 0; c < 128; c += 4){
      float f00=Wf1[(c+0)*128+o], f01=Wf1[(c+1)*128+o], f02=Wf1[(c+2)*128+o], f03=Wf1[(c+3)*128+o];
      float f10=Wf1[16384+(c+0)*128+o], f11=Wf1[16384+(c+1)*128+o], f12=Wf1[16384+(c+2)*128+o], f13=Wf1[16384+(c+3)*128+o];
      float g00=Wg1[(c+0)*128+o], g01=Wg1[(c+1)*128+o], g02=Wg1[(c+2)*128+o], g03=Wg1[(c+3)*128+o];
      float g10=Wg1[16384+(c+0)*128+o], g11=Wg1[16384+(c+1)*128+o], g12=Wg1[16384+(c+2)*128+o], g13=Wg1[16384+(c+3)*128+o];
      #pragma unroll
      for (int ii=0;ii<3;++ii){
        int i = ig + ii;
        float4 xa = *(const float4*)&sH1[(i*2+0)*128 + c];
        float4 xb = *(const float4*)&sH1[(i*2+1)*128 + c];
        af[ii] += xa.x*f00 + xa.y*f01 + xa.z*f02 + xa.w*f03
                + xb.x*f10 + xb.y*f11 + xb.z*f12 + xb.w*f13;
        ag[ii] += xa.x*g00 + xa.y*g01 + xa.z*g02 + xa.w*g03
                + xb.x*g10 + xb.y*g11 + xb.z*g12 + xb.w*g13;
      }
    }
    float bfv = bf_[128+o], bgv = bg_[128+o];
    #pragma unroll
    for (int ii=0;ii<3;++ii){
      int i = ig + ii;
      float f = tanhf(af[ii] + bfv);
      float g = 1.f/(1.f + expf(-(ag[ii] + bgv)));
      sH2[i*128 + o] = f*g + sH1[(i*2+1)*128 + o];
    }
  }
  __syncthreads();

  {
    int o6 = tid & 63, grp = tid >> 6;
    #pragma unroll
    for (int ii=0; ii<2; ++ii){
      int i = grp*2 + ii;
      if (i >= TROWS) continue;
      float acc = 0.f;
      for (int c = 0; c < 128; c += 4){
        float w0=Wout[(c+0)*64+o6], w1=Wout[(c+1)*64+o6],
              w2=Wout[(c+2)*64+o6], w3=Wout[(c+3)*64+o6];
        float4 xv = *(const float4*)&sH2[i*128 + c];
        acc += xv.x*w0 + xv.y*w1 + xv.z*w2 + xv.w*w3;
      }
      if (rowBN[i] >= 0) outb[rowBN[i]*64 + o6] = acc + bout[o6];
    }
  }
}

// ---------------- batchnorm ----------------
__global__ __launch_bounds__(256) void k_bnstats(const float* __restrict__ unb,
                                                 const float* __restrict__ hpr,
                                                 float* __restrict__ stats){
  int bid = blockIdx.x;
  int tensor = bid >> 6, c = bid & 63;
  const float* buf = tensor ? hpr : unb;
  float s1 = 0.f, s2 = 0.f;
  for (int r = threadIdx.x; r < NROWS; r += 256){
    float v = buf[r*64 + c];
    s1 += v; s2 += v*v;
  }
  __shared__ float r1[256], r2[256];
  r1[threadIdx.x]=s1; r2[threadIdx.x]=s2;
  __syncthreads();
  for (int s=128; s>0; s>>=1){
    if (threadIdx.x < s){ r1[threadIdx.x]+=r1[threadIdx.x+s]; r2[threadIdx.x]+=r2[threadIdx.x+s]; }
    __syncthreads();
  }
  if (threadIdx.x==0){
    float mean = r1[0]/(float)NROWS;
    float var  = r2[0]/(float)NROWS - mean*mean;
    stats[tensor*128 + c]      = mean;
    stats[tensor*128 + 64 + c] = rsqrtf(var + 1e-5f);
  }
}

// R7: float4 vectorized (grid 4000 -> 1000). 64%4==0 so a quad never wraps c.
__global__ __launch_bounds__(256) void k_bnapply(float* __restrict__ unb, float* __restrict__ hpr,
                                                 const float* __restrict__ stats,
                                                 const float* __restrict__ g1, const float* __restrict__ be1,
                                                 const float* __restrict__ gP, const float* __restrict__ beP){
  int idx = blockIdx.x*256 + threadIdx.x;          // one float4
  if (idx >= 2*NROWS*16) return;
  int tensor = idx >= NROWS*16;
  int local4 = idx - tensor*NROWS*16;
  int base = local4*4;
  int c = base & 63;
  float* buf = tensor ? hpr : unb;
  float4 v    = *(float4*)&buf[base];
  float4 mean = *(const float4*)&stats[tensor*128 + c];
  float4 rstd = *(const float4*)&stats[tensor*128 + 64 + c];
  float4 g    = tensor ? *(const float4*)&gP[c]  : *(const float4*)&g1[c];
  float4 bb   = tensor ? *(const float4*)&beP[c] : *(const float4*)&be1[c];
  v.x = g.x*(v.x-mean.x)*rstd.x + bb.x;
  v.y = g.y*(v.y-mean.y)*rstd.y + bb.y;
  v.z = g.z*(v.z-mean.z)*rstd.z + bb.z;
  v.w = g.w*(v.w-mean.w)*rstd.w + bb.w;
  *(float4*)&buf[base] = v;
}

// ---------------- flash attn, 16 rows/block, 2 rows/thread ----------------
// R6: PV 4-dim x 32-m tiling (verified -44us). R7: all staging vectorized to
// float4 (global loads + LDS writes where the dest is unpadded). kbuf keeps
// its 65-pad (conflict-free score reads) -> K/M/Wg LDS writes stay scalar,
// but their global loads are now float4. Final configuration.
template<int AMODE, int RELU, int FINAL, int ADD>
__global__ __launch_bounds__(256) void k_attn(
    const float* __restrict__ geo,
    const float* __restrict__ Qf, const float* __restrict__ Qb,
    const float* __restrict__ M,
    const float* __restrict__ Keysf, const float* __restrict__ Keysb,
    const float* __restrict__ X,
    const float* __restrict__ X0, const float* __restrict__ Z1,
    const float* __restrict__ Wg, const float* __restrict__ bg,
    float* __restrict__ cur, float* __restrict__ Y)
{
  __shared__ __align__(16) float kbuf[64][65];
  __shared__ __align__(16) float xbuf[64][64];
  __shared__ __align__(16) float vbuf[16][64];
  __shared__ __align__(16) float pbuf[16][64];

  int b = blockIdx.y, n0 = blockIdx.x*16;
  int tid = threadIdx.x;
  int nl = tid >> 5, ml = tid & 31;
  int nA = n0 + nl, nB = n0 + nl + 8;
  int mh = (ml >> 4) << 5;       // 0 or 32: m-half this lane owns in PV
  int d0 = (ml & 15) * 4;        // 4 output dims this lane owns in PV
  const float4 f40 = {0.f,0.f,0.f,0.f};
  float4 rrK4[4], rrX4[4], rrA4;

  if (AMODE != 0){
    {
      int r = tid >> 4, k4 = (tid & 15) * 4;   // 256 f4 = 1024 floats (16 rows x 64)
      int nn = n0 + r;
      float4 qv = f40;
      if (nn < N_){
        const float* qp = (AMODE == 1) ? &Qf[(b*N_+nn)*64+k4] : &Qb[nn*64+k4];
        qv = *(const float4*)qp;
      }
      *(float4*)&pbuf[r][k4] = qv;
    }
    #pragma unroll
    for (int ii = 0; ii < 4; ++ii){
      int fidx = tid + ii*256;                 // 1024 f4 = 4096 floats
      int r = fidx >> 4, k4 = (fidx & 15)*4;
      float4 v = *(const float4*)&M[b*4096 + r*64 + k4];
      kbuf[r][k4+0]=v.x; kbuf[r][k4+1]=v.y; kbuf[r][k4+2]=v.z; kbuf[r][k4+3]=v.w;
    }
    __syncthreads();
    float vxA = 0.f, vyA = 0.f, vxB = 0.f, vyB = 0.f;
    for (int kk = 0; kk < 64; ++kk){
      float qA = pbuf[nl][kk], qB = pbuf[nl+8][kk];
      float2 m2 = *(const float2*)&kbuf[kk][ml*2];
      vxA += qA*m2.x; vyA += qA*m2.y;
      vxB += qB*m2.x; vyB += qB*m2.y;
    }
    __syncthreads();
    vbuf[nl  ][ml*2] = vxA; vbuf[nl  ][ml*2+1] = vyA;
    vbuf[nl+8][ml*2] = vxB; vbuf[nl+8][ml*2+1] = vyB;
  }
  {
    if (AMODE != 0) __syncthreads();
    #pragma unroll
    for (int ii = 0; ii < 4; ++ii){
      int fidx = tid + ii*256;
      int mm = fidx >> 4, k4 = (fidx & 15)*4;
      if (AMODE != 0){
        const float* kp = (AMODE == 1) ? &Keysf[(b*N_+mm)*64+k4] : &Keysb[mm*64+k4];
        float4 kv = *(const float4*)kp;
        kbuf[mm][k4+0]=kv.x; kbuf[mm][k4+1]=kv.y; kbuf[mm][k4+2]=kv.z; kbuf[mm][k4+3]=kv.w;
      }
      *(float4*)&xbuf[mm][k4] = *(const float4*)&X[(b*N_+mm)*64+k4];
    }
    if (AMODE == 0){
      int r = tid >> 4, m4 = (tid & 15)*4;     // 256 f4 = 16 rows x 64 m
      int nn = n0 + r;
      float4 g0 = (nn < N_) ? *(const float4*)&geo[nn*N_ + m4] : f40;
      *(float4*)&pbuf[r][m4] = g0;
    }
    __syncthreads();
  }

  float m_runA = -1e30f, l_runA = 0.f;
  float m_runB = -1e30f, l_runB = 0.f;
  float accA[4] = {0.f,0.f,0.f,0.f};
  float accB[4] = {0.f,0.f,0.f,0.f};

  for (int ci = 0; ci < 8; ++ci){
    int m0 = ci*64;
    if (ci < 7){
      #pragma unroll
      for (int ii=0; ii<4; ++ii){
        int fidx = tid + ii*256;
        int mm = fidx >> 4, k4 = (fidx & 15)*4;
        int m = m0 + 64 + mm;
        if (AMODE != 0){
          if (m < N_){
            const float* kp = (AMODE == 1) ? &Keysf[(b*N_+m)*64+k4] : &Keysb[m*64+k4];
            rrK4[ii] = *(const float4*)kp;
          } else rrK4[ii] = f40;
        }
        rrX4[ii] = (m < N_) ? *(const float4*)&X[(b*N_+m)*64+k4] : f40;
      }
      if (AMODE == 0){
        int r = tid >> 4, m4 = (tid & 15)*4;
        int nn = n0 + r, m = m0 + 64 + m4;
        rrA4 = (nn < N_ && m < N_) ? *(const float4*)&geo[nn*N_ + m] : f40;
      }
    }
    if (AMODE != 0){
      float s0A = 0.f, s1A = 0.f, s0B = 0.f, s1B = 0.f;
      for (int kk = 0; kk < 64; kk += 4){
        float4 qA = *(const float4*)&vbuf[nl  ][kk];
        float4 qB = *(const float4*)&vbuf[nl+8][kk];
        float4 k0 = *(const float4*)&kbuf[ml   ][kk];
        float4 k1 = *(const float4*)&kbuf[ml+32][kk];
        s0A += qA.x*k0.x + qA.y*k0.y + qA.z*k0.z + qA.w*k0.w;
        s1A += qA.x*k1.x + qA.y*k1.y + qA.z*k1.z + qA.w*k1.w;
        s0B += qB.x*k0.x + qB.y*k0.y + qB.z*k0.z + qB.w*k0.w;
        s1B += qB.x*k1.x + qB.y*k1.y + qB.z*k1.z + qB.w*k1.w;
      }
      float v0A = (m0 + ml      < N_) ? (RELU ? fmaxf(s0A, 0.f) : s0A) : -1e30f;
      float v1A = (m0 + ml + 32 < N_) ? (RELU ? fmaxf(s1A, 0.f) : s1A) : -1e30f;
      float v0B = (m0 + ml      < N_) ? (RELU ? fmaxf(s0B, 0.f) : s0B) : -1e30f;
      float v1B = (m0 + ml + 32 < N_) ? (RELU ? fmaxf(s1B, 0.f) : s1B) : -1e30f;
      float cmaxA = fmaxf(v0A, v1A), cmaxB = fmaxf(v0B, v1B);
      #pragma unroll
      for (int msk = 1; msk < 32; msk <<= 1){
        cmaxA = fmaxf(cmaxA, __shfl_xor(cmaxA, msk, 32));
        cmaxB = fmaxf(cmaxB, __shfl_xor(cmaxB, msk, 32));
      }
      float mnewA = fmaxf(m_runA, cmaxA), mnewB = fmaxf(m_runB, cmaxB);
      float scaleA = expf(m_runA - mnewA), scaleB = expf(m_runB - mnewB);
      float p0A = expf(v0A - mnewA), p1A = expf(v1A - mnewA);
      float p0B = expf(v0B - mnewB), p1B = expf(v1B - mnewB);
      float lcA = p0A + p1A, lcB = p0B + p1B;
      #pragma unroll
      for (int msk = 1; msk < 32; msk <<= 1){
        lcA += __shfl_xor(lcA, msk, 32);
        lcB += __shfl_xor(lcB, msk, 32);
      }
      l_runA = l_runA*scaleA + lcA; m_runA = mnewA;
      l_runB = l_runB*scaleB + lcB; m_runB = mnewB;
      #pragma unroll
      for (int d=0; d<4; ++d){ accA[d] *= scaleA; accB[d] *= scaleB; }
      pbuf[nl  ][ml]    = p0A;
      pbuf[nl  ][ml+32] = p1A;
      pbuf[nl+8][ml]    = p0B;
      pbuf[nl+8][ml+32] = p1B;
    }
    __syncthreads();
    #pragma unroll
    for (int mm = 0; mm < 32; mm += 4){
      float4 pA = *(const float4*)&pbuf[nl  ][mh + mm];
      float4 pB = *(const float4*)&pbuf[nl+8][mh + mm];
      float4 x0 = *(const float4*)&xbuf[mh+mm+0][d0];
      float4 x1 = *(const float4*)&xbuf[mh+mm+1][d0];
      float4 x2 = *(const float4*)&xbuf[mh+mm+2][d0];
      float4 x3 = *(const float4*)&xbuf[mh+mm+3][d0];
      accA[0] += pA.x*x0.x + pA.y*x1.x + pA.z*x2.x + pA.w*x3.x;
      accA[1] += pA.x*x0.y + pA.y*x1.y + pA.z*x2.y + pA.w*x3.y;
      accA[2] += pA.x*x0.z + pA.y*x1.z + pA.z*x2.z + pA.w*x3.z;
      accA[3] += pA.x*x0.w + pA.y*x1.w + pA.z*x2.w + pA.w*x3.w;
      accB[0] += pB.x*x0.x + pB.y*x1.x + pB.z*x2.x + pB.w*x3.x;
      accB[1] += pB.x*x0.y + pB.y*x1.y + pB.z*x2.y + pB.w*x3.y;
      accB[2] += pB.x*x0.z + pB.y*x1.z + pB.z*x2.z + pB.w*x3.z;
      accB[3] += pB.x*x0.w + pB.y*x1.w + pB.z*x2.w + pB.w*x3.w;
    }
    __syncthreads();
    if (ci < 7){
      #pragma unroll
      for (int ii=0; ii<4; ++ii){
        int fidx = tid + ii*256;
        int mm = fidx >> 4, k4 = (fidx & 15)*4;
        if (AMODE != 0){
          float4 kv = rrK4[ii];
          kbuf[mm][k4+0]=kv.x; kbuf[mm][k4+1]=kv.y; kbuf[mm][k4+2]=kv.z; kbuf[mm][k4+3]=kv.w;
        }
        *(float4*)&xbuf[mm][k4] = rrX4[ii];
      }
      if (AMODE == 0){
        int r = tid >> 4, m4 = (tid & 15)*4;
        *(float4*)&pbuf[r][m4] = rrA4;
      }
      __syncthreads();
    }
  }
  // recombine the two m-halves (lane pairs ml, ml^16 share nl)
  #pragma unroll
  for (int d=0; d<4; ++d){
    accA[d] += __shfl_xor(accA[d], 16, 32);
    accB[d] += __shfl_xor(accB[d], 16, 32);
  }
  if (AMODE != 0){
    float invA = 1.f / l_runA, invB = 1.f / l_runB;
    #pragma unroll
    for (int d=0; d<4; ++d){ accA[d] *= invA; accB[d] *= invB; }
  }

  if (!FINAL){
    if (ml < 16){
      if (nA < N_){
        float4 o4; o4.x = accA[0]; o4.y = accA[1]; o4.z = accA[2]; o4.w = accA[3];
        *(float4*)&Y[(b*N_+nA)*64 + d0] = o4;
      }
      if (nB < N_){
        float4 o4; o4.x = accB[0]; o4.y = accB[1]; o4.z = accB[2]; o4.w = accB[3];
        *(float4*)&Y[(b*N_+nB)*64 + d0] = o4;
      }
    }
    return;
  }

  {
    if (ml < 16){
      float4 svA = {0.f,0.f,0.f,0.f}, svB = {0.f,0.f,0.f,0.f};
      if (nA < N_){
        int row = b*N_ + nA;
        float4 x0v = *(const float4*)&X0[row*64 + d0];
        float4 z1v = *(const float4*)&Z1[row*64 + d0];
        svA.x = accA[0] + x0v.x + z1v.x;
        svA.y = accA[1] + x0v.y + z1v.y;
        svA.z = accA[2] + x0v.z + z1v.z;
        svA.w = accA[3] + x0v.w + z1v.w;
      }
      if (nB < N_){
        int row = b*N_ + nB;
        float4 x0v = *(const float4*)&X0[row*64 + d0];
        float4 z1v = *(const float4*)&Z1[row*64 + d0];
        svB.x = accB[0] + x0v.x + z1v.x;
        svB.y = accB[1] + x0v.y + z1v.y;
        svB.z = accB[2] + x0v.z + z1v.z;
        svB.w = accB[3] + x0v.w + z1v.w;
      }
      *(float4*)&vbuf[nl  ][d0] = svA;
      *(float4*)&vbuf[nl+8][d0] = svB;
    }
    #pragma unroll
    for (int ii = 0; ii < 4; ++ii){
      int fidx = tid + ii*256;
      int r = fidx >> 4, k4 = (fidx & 15)*4;
      float4 wv = *(const float4*)&Wg[r*64 + k4];
      kbuf[r][k4+0]=wv.x; kbuf[r][k4+1]=wv.y; kbuf[r][k4+2]=wv.z; kbuf[r][k4+3]=wv.w;
    }
    __syncthreads();
    float oxA = 0.f, oyA = 0.f, oxB = 0.f, oyB = 0.f;
    for (int kk = 0; kk < 64; ++kk){
      float sA = vbuf[nl][kk], sB = vbuf[nl+8][kk];
      float2 w2 = *(const float2*)&kbuf[kk][ml*2];
      oxA += sA*w2.x; oyA += sA*w2.y;
      oxB += sB*w2.x; oyB += sB*w2.y;
    }
    float2 bv = *(const float2*)&bg[ml*2];
    if (nA < N_){
      int row = b*N_ + nA;
      float vx = oxA + bv.x, vy = oyA + bv.y;
      if (ADD){
        float2 old = *(const float2*)&cur[row*64 + ml*2];
        vx += old.x; vy += old.y;
      }
      float2 o2; o2.x = vx; o2.y = vy;
      *(float2*)&cur[row*64 + ml*2] = o2;
    }
    if (nB < N_){
      int row = b*N_ + nB;
      float vx = oxB + bv.x, vy = oyB + bv.y;
      if (ADD){
        float2 old = *(const float2*)&cur[row*64 + ml*2];
        vx += old.x; vy += old.y;
      }
      float2 o2; o2.x = vx; o2.y = vy;
      *(float2*)&cur[row*64 + ml*2] = o2;
    }
  }
}

// ---------------- pass 1 with raw-score caching (16 rows/block) ----------------
template<int AMODE, int RELU>
__global__ __launch_bounds__(256) void k_attn_p1(
    const float* __restrict__ Qf, const float* __restrict__ Qb,
    const float* __restrict__ M,
    const float* __restrict__ Keysf, const float* __restrict__ Keysb,
    const float* __restrict__ X,
    float* __restrict__ Pb, float* __restrict__ Y)
{
  __shared__ __align__(16) float kbuf[64][65];
  __shared__ __align__(16) float xbuf[64][64];
  __shared__ __align__(16) float vbuf[16][64];
  __shared__ __align__(16) float pbuf[16][64];

  int b = blockIdx.y, n0 = blockIdx.x*16;
  int tid = threadIdx.x;
  int nl = tid >> 5, ml = tid & 31;
  int nA = n0 + nl, nB = n0 + nl + 8;
  int mh = (ml >> 4) << 5;
  int d0 = (ml & 15) * 4;
  const float4 f40 = {0.f,0.f,0.f,0.f};
  float4 rrK4[4], rrX4[4];

  {
    int r = tid >> 4, k4 = (tid & 15) * 4;
    int nn = n0 + r;
    float4 qv = f40;
    if (nn < N_){
      const float* qp = (AMODE == 1) ? &Qf[(b*N_+nn)*64+k4] : &Qb[nn*64+k4];
      qv = *(const float4*)qp;
    }
    *(float4*)&pbuf[r][k4] = qv;
  }
  #pragma unroll
  for (int ii = 0; ii < 4; ++ii){
    int fidx = tid + ii*256;
    int r = fidx >> 4, k4 = (fidx & 15)*4;
    float4 v = *(const float4*)&M[b*4096 + r*64 + k4];
    kbuf[r][k4+0]=v.x; kbuf[r][k4+1]=v.y; kbuf[r][k4+2]=v.z; kbuf[r][k4+3]=v.w;
  }
  __syncthreads();
  float vxA = 0.f, vyA = 0.f, vxB = 0.f, vyB = 0.f;
  for (int kk = 0; kk < 64; ++kk){
    float qA = pbuf[nl][kk], qB = pbuf[nl+8][kk];
    float2 m2 = *(const float2*)&kbuf[kk][ml*2];
    vxA += qA*m2.x; vyA += qA*m2.y;
    vxB += qB*m2.x; vyB += qB*m2.y;
  }
  __syncthreads();
  vbuf[nl  ][ml*2] = vxA; vbuf[nl  ][ml*2+1] = vyA;
  vbuf[nl+8][ml*2] = vxB; vbuf[nl+8][ml*2+1] = vyB;
  __syncthreads();
  #pragma unroll
  for (int ii = 0; ii < 4; ++ii){
    int fidx = tid + ii*256;
    int mm = fidx >> 4, k4 = (fidx & 15)*4;
    const float* kp = (AMODE == 1) ? &Keysf[(b*N_+mm)*64+k4] : &Keysb[mm*64+k4];
    float4 kv = *(const float4*)kp;
    kbuf[mm][k4+0]=kv.x; kbuf[mm][k4+1]=kv.y; kbuf[mm][k4+2]=kv.z; kbuf[mm][k4+3]=kv.w;
    *(float4*)&xbuf[mm][k4] = *(const float4*)&X[(b*N_+mm)*64+k4];
  }
  __syncthreads();

  float m_runA = -1e30f, l_runA = 0.f;
  float m_runB = -1e30f, l_runB = 0.f;
  float accA[4] = {0.f,0.f,0.f,0.f};
  float accB[4] = {0.f,0.f,0.f,0.f};

  for (int ci = 0; ci < 8; ++ci){
    int m0 = ci*64;
    if (ci < 7){
      #pragma unroll
      for (int ii=0; ii<4; ++ii){
        int fidx = tid + ii*256;
        int mm = fidx >> 4, k4 = (fidx & 15)*4;
        int m = m0 + 64 + mm;
        if (m < N_){
          const float* kp = (AMODE == 1) ? &Keysf[(b*N_+m)*64+k4] : &Keysb[m*64+k4];
          rrK4[ii] = *(const float4*)kp;
          rrX4[ii] = *(const float4*)&X[(b*N_+m)*64+k4];
        } else { rrK4[ii] = f40; rrX4[ii] = f40; }
      }
    }
    {
      float s0A = 0.f, s1A = 0.f, s0B = 0.f, s1B = 0.f;
      for (int kk = 0; kk < 64; kk += 4){
        float4 qA = *(const float4*)&vbuf[nl  ][kk];
        float4 qB = *(const float4*)&vbuf[nl+8][kk];
        float4 k0 = *(const float4*)&kbuf[ml   ][kk];
        float4 k1 = *(const float4*)&kbuf[ml+32][kk];
        s0A += qA.x*k0.x + qA.y*k0.y + qA.z*k0.z + qA.w*k0.w;
        s1A += qA.x*k1.x + qA.y*k1.y + qA.z*k1.z + qA.w*k1.w;
        s0B += qB.x*k0.x + qB.y*k0.y + qB.z*k0.z + qB.w*k0.w;
        s1B += qB.x*k1.x + qB.y*k1.y + qB.z*k1.z + qB.w*k1.w;
      }
      float v0A = (m0 + ml      < N_) ? (RELU ? fmaxf(s0A, 0.f) : s0A) : -1e30f;
      float v1A = (m0 + ml + 32 < N_) ? (RELU ? fmaxf(s1A, 0.f) : s1A) : -1e30f;
      float v0B = (m0 + ml      < N_) ? (RELU ? fmaxf(s0B, 0.f) : s0B) : -1e30f;
      float v1B = (m0 + ml + 32 < N_) ? (RELU ? fmaxf(s1B, 0.f) : s1B) : -1e30f;
      if (nA < N_){
        Pb[((long)(b*N_+nA))*512 + m0 + ml]      = v0A;
        Pb[((long)(b*N_+nA))*512 + m0 + ml + 32] = v1A;
      }
      if (nB < N_){
        Pb[((long)(b*N_+nB))*512 + m0 + ml]      = v0B;
        Pb[((long)(b*N_+nB))*512 + m0 + ml + 32] = v1B;
      }
      float cmaxA = fmaxf(v0A, v1A), cmaxB = fmaxf(v0B, v1B);
      #pragma unroll
      for (int msk = 1; msk < 32; msk <<= 1){
        cmaxA = fmaxf(cmaxA, __shfl_xor(cmaxA, msk, 32));
        cmaxB = fmaxf(cmaxB, __shfl_xor(cmaxB, msk, 32));
      }
      float mnewA = fmaxf(m_runA, cmaxA), mnewB = fmaxf(m_runB, cmaxB);
      float scaleA = expf(m_runA - mnewA), scaleB = expf(m_runB - mnewB);
      float p0A = expf(v0A - mnewA), p1A = expf(v1A - mnewA);
      float p0B = expf(v0B - mnewB), p1B = expf(v1B - mnewB);
      float lcA = p0A + p1A, lcB = p0B + p1B;
      #pragma unroll
      for (int msk = 1; msk < 32; msk <<= 1){
        lcA += __shfl_xor(lcA, msk, 32);
        lcB += __shfl_xor(lcB, msk, 32);
      }
      l_runA = l_runA*scaleA + lcA; m_runA = mnewA;
      l_runB = l_runB*scaleB + lcB; m_runB = mnewB;
      #pragma unroll
      for (int d=0; d<4; ++d){ accA[d] *= scaleA; accB[d] *= scaleB; }
      pbuf[nl  ][ml]    = p0A;
      pbuf[nl  ][ml+32] = p1A;
      pbuf[nl+8][ml]    = p0B;
      pbuf[nl+8][ml+32] = p1B;
    }
    __syncthreads();
    #pragma unroll
    for (int mm = 0; mm < 32; mm += 4){
      float4 pA = *(const float4*)&pbuf[nl  ][mh + mm];
      float4 pB = *(const float4*)&pbuf[nl+8][mh + mm];
      float4 x0 = *(const float4*)&xbuf[mh+mm+0][d0];
      float4 x1 = *(const float4*)&xbuf[mh+mm+1][d0];
      float4 x2 = *(const float4*)&xbuf[mh+mm+2][d0];
      float4 x3 = *(const float4*)&xbuf[mh+mm+3][d0];
      accA[0] += pA.x*x0.x + pA.y*x1.x + pA.z*x2.x + pA.w*x3.x;
      accA[1] += pA.x*x0.y + pA.y*x1.y + pA.z*x2.y + pA.w*x3.y;
      accA[2] += pA.x*x0.z + pA.y*x1.z + pA.z*x2.z + pA.w*x3.z;
      accA[3] += pA.x*x0.w + pA.y*x1.w + pA.z*x2.w + pA.w*x3.w;
      accB[0] += pB.x*x0.x + pB.y*x1.x + pB.z*x2.x + pB.w*x3.x;
      accB[1] += pB.x*x0.y + pB.y*x1.y + pB.z*x2.y + pB.w*x3.y;
      accB[2] += pB.x*x0.z + pB.y*x1.z + pB.z*x2.z + pB.w*x3.z;
      accB[3] += pB.x*x0.w + pB.y*x1.w + pB.z*x2.w + pB.w*x3.w;
    }
    __syncthreads();
    if (ci < 7){
      #pragma unroll
      for (int ii=0; ii<4; ++ii){
        int fidx = tid + ii*256;
        int mm = fidx >> 4, k4 = (fidx & 15)*4;
        float4 kv = rrK4[ii];
        kbuf[mm][k4+0]=kv.x; kbuf[mm][k4+1]=kv.y; kbuf[mm][k4+2]=kv.z; kbuf[mm][k4+3]=kv.w;
        *(float4*)&xbuf[mm][k4] = rrX4[ii];
      }
      __syncthreads();
    }
  }
  #pragma unroll
  for (int d=0; d<4; ++d){
    accA[d] += __shfl_xor(accA[d], 16, 32);
    accB[d] += __shfl_xor(accB[d], 16, 32);
  }
  float invA = 1.f / l_runA, invB = 1.f / l_runB;
  #pragma unroll
  for (int d=0; d<4; ++d){ accA[d] *= invA; accB[d] *= invB; }
  if (ml < 16){
    if (nA < N_){
      float4 o4; o4.x = accA[0]; o4.y = accA[1]; o4.z = accA[2]; o4.w = accA[3];
      *(float4*)&Y[(b*N_+nA)*64 + d0] = o4;
    }
    if (nB < N_){
      float4 o4; o4.x = accB[0]; o4.y = accB[1]; o4.z = accB[2]; o4.w = accB[3];
      *(float4*)&Y[(b*N_+nB)*64 + d0] = o4;
    }
  }
}

// ---------------- pass 2 from cached scores (16 rows/block) ----------------
template<int ADD>
__global__ __launch_bounds__(256) void k_attn_p2(
    const float* __restrict__ Pb,
    const float* __restrict__ X,      // zt1
    const float* __restrict__ X0,     // residual base
    const float* __restrict__ Wg, const float* __restrict__ bg,
    float* __restrict__ cur)
{
  __shared__ __align__(16) float pbuf[16][516];
  __shared__ __align__(16) float xbuf[64][64];
  __shared__ __align__(16) float vbuf[16][64];

  int b = blockIdx.y, n0 = blockIdx.x*16;
  int tid = threadIdx.x;
  int nl = tid >> 5, ml = tid & 31;
  int nA = n0 + nl, nB = n0 + nl + 8;
  int mh = (ml >> 4) << 5;
  int d0 = (ml & 15) * 4;
  float4 rrX4[4];
  const float4 f40 = {0.f,0.f,0.f,0.f};
  const float4 fneg = {-1e30f,-1e30f,-1e30f,-1e30f};

  #pragma unroll
  for (int ii = 0; ii < 8; ++ii){
    int fidx = tid + ii*256;              // 2048 f4 = 16 rows x 512
    int r = fidx >> 7, m4 = (fidx & 127)*4;
    int nn = n0 + r;
    float4 v = (nn < N_) ? *(const float4*)&Pb[((long)(b*N_+nn))*512 + m4] : fneg;
    *(float4*)&pbuf[r][m4] = v;           // row stride 516 floats = 2064 B, 16B-aligned
  }
  __syncthreads();
  float lmaxA = -1e30f, lmaxB = -1e30f;
  for (int m = ml; m < 512; m += 32){
    lmaxA = fmaxf(lmaxA, pbuf[nl  ][m]);
    lmaxB = fmaxf(lmaxB, pbuf[nl+8][m]);
  }
  #pragma unroll
  for (int msk=1; msk<32; msk<<=1){
    lmaxA = fmaxf(lmaxA, __shfl_xor(lmaxA, msk, 32));
    lmaxB = fmaxf(lmaxB, __shfl_xor(lmaxB, msk, 32));
  }
  float lsumA = 0.f, lsumB = 0.f;
  for (int m = ml; m < 512; m += 32){
    float pA = expf(pbuf[nl  ][m] - lmaxA);
    float pB = expf(pbuf[nl+8][m] - lmaxB);
    pbuf[nl  ][m] = pA;
    pbuf[nl+8][m] = pB;
    lsumA += pA; lsumB += pB;
  }
  #pragma unroll
  for (int msk=1; msk<32; msk<<=1){
    lsumA += __shfl_xor(lsumA, msk, 32);
    lsumB += __shfl_xor(lsumB, msk, 32);
  }
  float invA = 1.f/lsumA, invB = 1.f/lsumB;
  for (int m = ml; m < 512; m += 32){
    pbuf[nl  ][m] *= invA;
    pbuf[nl+8][m] *= invB;
  }

  #pragma unroll
  for (int ii=0; ii<4; ++ii){
    int fidx = tid + ii*256;
    int mm = fidx >> 4, k4 = (fidx & 15)*4;
    *(float4*)&xbuf[mm][k4] = *(const float4*)&X[(b*N_+mm)*64+k4];
  }
  __syncthreads();

  float accA[4] = {0.f,0.f,0.f,0.f};
  float accB[4] = {0.f,0.f,0.f,0.f};
  for (int ci = 0; ci < 8; ++ci){
    int m0 = ci*64;
    if (ci < 7){
      #pragma unroll
      for (int ii=0; ii<4; ++ii){
        int fidx = tid + ii*256;
        int mm = fidx >> 4, k4 = (fidx & 15)*4;
        int m = m0+64+mm;
        rrX4[ii] = (m < N_) ? *(const float4*)&X[(b*N_+m)*64+k4] : f40;
      }
    }
    #pragma unroll
    for (int mm = 0; mm < 32; mm += 4){
      float4 pA = *(const float4*)&pbuf[nl  ][m0 + mh + mm];
      float4 pB = *(const float4*)&pbuf[nl+8][m0 + mh + mm];
      float4 x0 = *(const float4*)&xbuf[mh+mm+0][d0];
      float4 x1 = *(const float4*)&xbuf[mh+mm+1][d0];
      float4 x2 = *(const float4*)&xbuf[mh+mm+2][d0];
      float4 x3 = *(const float4*)&xbuf[mh+mm+3][d0];
      accA[0] += pA.x*x0.x + pA.y*x1.x + pA.z*x2.x + pA.w*x3.x;
      accA[1] += pA.x*x0.y + pA.y*x1.y + pA.z*x2.y + pA.w*x3.y;
      accA[2] += pA.x*x0.z + pA.y*x1.z + pA.z*x2.z + pA.w*x3.z;
      accA[3] += pA.x*x0.w + pA.y*x1.w + pA.z*x2.w + pA.w*x3.w;
      accB[0] += pB.x*x0.x + pB.y*x1.x + pB.z*x2.x + pB.w*x3.x;
      accB[1] += pB.x*x0.y + pB.y*x1.y + pB.z*x2.y + pB.w*x3.y;
      accB[2] += pB.x*x0.z + pB.y*x1.z + pB.z*x2.z + pB.w*x3.z;
      accB[3] += pB.x*x0.w + pB.y*x1.w + pB.z*x2.w + pB.w*x3.w;
    }
    __syncthreads();
    if (ci < 7){
      #pragma unroll
      for (int ii=0; ii<4; ++ii){
        int fidx = tid + ii*256;
        int mm = fidx >> 4, k4 = (fidx & 15)*4;
        *(float4*)&xbuf[mm][k4] = rrX4[ii];
      }
      __syncthreads();
    }
  }
  #pragma unroll
  for (int d=0; d<4; ++d){
    accA[d] += __shfl_xor(accA[d], 16, 32);
    accB[d] += __shfl_xor(accB[d], 16, 32);
  }

  {
    if (ml < 16){
      float4 svA = {0.f,0.f,0.f,0.f}, svB = {0.f,0.f,0.f,0.f};
      if (nA < N_){
        int row = b*N_ + nA;
        float4 x0v = *(const float4*)&X0[row*64 + d0];
        float4 z1v = *(const float4*)&X[row*64 + d0];
        svA.x = accA[0] + x0v.x + z1v.x;
        svA.y = accA[1] + x0v.y + z1v.y;
        svA.z = accA[2] + x0v.z + z1v.z;
        svA.w = accA[3] + x0v.w + z1v.w;
      }
      if (nB < N_){
        int row = b*N_ + nB;
        float4 x0v = *(const float4*)&X0[row*64 + d0];
        float4 z1v = *(const float4*)&X[row*64 + d0];
        svB.x = accB[0] + x0v.x + z1v.x;
        svB.y = accB[1] + x0v.y + z1v.y;
        svB.z = accB[2] + x0v.z + z1v.z;
        svB.w = accB[3] + x0v.w + z1v.w;
      }
      *(float4*)&vbuf[nl  ][d0] = svA;
      *(float4*)&vbuf[nl+8][d0] = svB;
    }
    #pragma unroll
    for (int ii=0; ii<4; ++ii){
      int fidx = tid + ii*256;
      int r = fidx >> 4, k4 = (fidx & 15)*4;
      *(float4*)&xbuf[r][k4] = *(const float4*)&Wg[r*64 + k4];
    }
    __syncthreads();
    float oxA = 0.f, oyA = 0.f, oxB = 0.f, oyB = 0.f;
    for (int kk = 0; kk < 64; ++kk){
      float sA = vbuf[nl][kk], sB = vbuf[nl+8][kk];
      float2 w2 = *(const float2*)&xbuf[kk][ml*2];
      oxA += sA*w2.x; oyA += sA*w2.y;
      oxB += sB*w2.x; oyB += sB*w2.y;
    }
    float2 bv = *(const float2*)&bg[ml*2];
    if (nA < N_){
      int row = b*N_ + nA;
      float vx = oxA + bv.x, vy = oyA + bv.y;
      if (ADD){
        float2 old = *(const float2*)&cur[row*64 + ml*2];
        vx += old.x; vy += old.y;
      }
      float2 o2; o2.x = vx; o2.y = vy;
      *(float2*)&cur[row*64 + ml*2] = o2;
    }
    if (nB < N_){
      int row = b*N_ + nB;
      float vx = oxB + bv.x, vy = oyB + bv.y;
      if (ADD){
        float2 old = *(const float2*)&cur[row*64 + ml*2];
        vx += old.x; vy += old.y;
      }
      float2 o2; o2.x = vx; o2.y = vy;
      *(float2*)&cur[row*64 + ml*2] = o2;
    }
  }
}

// ---------------- output head (R5: 8 rows/block, halves W1 L2 re-reads) ------
__global__ __launch_bounds__(128) void k_out(const float* __restrict__ cur,
                                             const float* __restrict__ W1, const float* __restrict__ bb1,
                                             const float* __restrict__ W2, const float* __restrict__ bb2,
                                             float* __restrict__ out){
  __shared__ float ch[8][64];
  __shared__ float hid[8*1200];
  int tid = threadIdx.x;
  int rbase = blockIdx.x*8;
  for (int idx = tid; idx < 512; idx += 128){
    int r = idx >> 6, h = idx & 63;
    ch[r][h] = cur[(rbase+r)*64 + h];
  }
  __syncthreads();
  for (int job = tid; job < 1200; job += 128){
    int t = job / 100, f = job - t*100;
    float bb = bb1[t*100+f];
    float a0=bb,a1=bb,a2=bb,a3=bb,a4=bb,a5=bb,a6=bb,a7=bb;
    for (int h = 0; h < 64; ++h){
      float w = W1[(t*64+h)*100 + f];
      a0 += ch[0][h]*w; a1 += ch[1][h]*w; a2 += ch[2][h]*w; a3 += ch[3][h]*w;
      a4 += ch[4][h]*w; a5 += ch[5][h]*w; a6 += ch[6][h]*w; a7 += ch[7][h]*w;
    }
    hid[0*1200+job] = (a0 > 0.f) ? a0 : expm1f(a0);
    hid[1*1200+job] = (a1 > 0.f) ? a1 : expm1f(a1);
    hid[2*1200+job] = (a2 > 0.f) ? a2 : expm1f(a2);
    hid[3*1200+job] = (a3 > 0.f) ? a3 : expm1f(a3);
    hid[4*1200+job] = (a4 > 0.f) ? a4 : expm1f(a4);
    hid[5*1200+job] = (a5 > 0.f) ? a5 : expm1f(a5);
    hid[6*1200+job] = (a6 > 0.f) ? a6 : expm1f(a6);
    hid[7*1200+job] = (a7 > 0.f) ? a7 : expm1f(a7);
  }
  __syncthreads();
  for (int jb = tid; jb < 192; jb += 128){
    int r = jb / 24, rem = jb % 24;
    int t = rem >> 1, o = rem & 1;
    float a = bb2[t*2+o];
    const float* hp = hid + r*1200 + t*100;
    for (int f = 0; f < 100; ++f) a += hp[f] * W2[(t*100+f)*2+o];
    out[(rbase+r)*24 + t*2+o] = a;
  }
}

// ---------------- launch ----------------
extern "C" void kernel_launch(void* const* d_in, const int* in_sizes, int n_in,
                              void* d_out, int out_size, void* d_ws, size_t ws_size,
                              hipStream_t stream)
{
  const float* x        = (const float*)d_in[0];
  const float* geo      = (const float*)d_in[2];
  const float* fcx_W    = (const float*)d_in[3];
  const float* fcx_b    = (const float*)d_in[4];
  const float* env_cb   = (const float*)d_in[5];
  const float* nodes_cb = (const float*)d_in[6];
  const float* w_v      = (const float*)d_in[7];
  const float* w_k      = (const float*)d_in[8];
  const float* w_q      = (const float*)d_in[9];
  const float* core_W   = (const float*)d_in[10];
  const float* core_b   = (const float*)d_in[11];
  const float* tN_Win   = (const float*)d_in[12];
  const float* tN_bin   = (const float*)d_in[13];
  const float* tN_Wf    = (const float*)d_in[14];
  const float* tN_bf    = (const float*)d_in[15];
  const float* tN_Wg    = (const float*)d_in[16];
  const float* tN_bg    = (const float*)d_in[17];
  const float* tN_Wout  = (const float*)d_in[18];
  const float* tN_bout  = (const float*)d_in[19];
  const float* tP_Win   = (const float*)d_in[20];
  const float* tP_bin   = (const float*)d_in[21];
  const float* tP_Wf    = (const float*)d_in[22];
  const float* tP_bf    = (const float*)d_in[23];
  const float* tP_Wg    = (const float*)d_in[24];
  const float* tP_bg    = (const float*)d_in[25];
  const float* tP_Wout  = (const float*)d_in[26];
  const float* tP_bout  = (const float*)d_in[27];
  const float* bn1_g    = (const float*)d_in[28];
  const float* bn1_b    = (const float*)d_in[29];
  const float* bnP_g    = (const float*)d_in[30];
  const float* bnP_b    = (const float*)d_in[31];
  const float* gcn1_W   = (const float*)d_in[32];
  const float* gcn1_b   = (const float*)d_in[33];
  const float* gcn2_W   = (const float*)d_in[34];
  const float* gcn2_b   = (const float*)d_in[35];
  const float* gcnp_W   = (const float*)d_in[36];
  const float* gcnp_b   = (const float*)d_in[37];
  const float* nv_p1    = (const float*)d_in[38];
  const float* nv_p2    = (const float*)d_in[39];
  const float* nv_p3    = (const float*)d_in[40];
  const float* nv_pk    = (const float*)d_in[41];
  const float* out_W1   = (const float*)d_in[42];
  const float* out_b1   = (const float*)d_in[43];
  const float* out_W2   = (const float*)d_in[44];
  const float* out_b2   = (const float*)d_in[45];
  const int*   t_pos    = (const int*)d_in[46];
  const int*   ind      = (const int*)d_in[47];

  // Base: 4096 B + 2,223,616 floats. Pb: +4,096,000 floats (gate 25.28 MB).
  // TE (212,480 floats) ALIASES Pb's start: consumed by k_tcn2 before p1 writes Pb.
  // Header: node_list[512] ints, off[16] ints, chunkOff[21] ints -> < 4096 B.
  int* node_list = (int*)d_ws;
  int* off       = node_list + 512;
  float* F = (float*)((char*)d_ws + 4096);
  float* temb   = F + 0;
  float* core_f = F + 12288;
  float* tmp1   = F + 77824;
  float* stats  = F + 143360;
  float* matq   = F + 143616;
  float* unb    = F + 175616;
  float* hpr    = F + 687616;
  float* cur    = F + 1199616;
  float* zt1    = F + 1711616;
  float* Pb     = F + 2223616;
  float* TE     = Pb;            // alias (disjoint lifetimes)
  bool useP = ws_size >= (size_t)(4096 + (size_t)(2223616 + 4096000)*4);

  k_matq <<<dim3(125), dim3(256), 0, stream>>>(nodes_cb, w_q, matq);
  k_route<<<dim3(1),   dim3(256), 0, stream>>>(env_cb, w_v, w_k, matq, node_list, off);
  k_temb <<<dim3(1),   dim3(192), 0, stream>>>(t_pos, temb);
  k_core <<<dim3(256), dim3(256), 0, stream>>>(temb, core_W, core_b, core_f);
  if (useP){
    k_tprep<<<dim3(20, 81), dim3(128), 0, stream>>>(temb, fcx_W, fcx_b, tN_Win, tP_Win, TE);
    k_tcn2 <<<dim3(NTCN2), dim3(256), 0, stream>>>(x, TE, node_list, off,
        tN_bin, tN_Wf, tN_bf, tN_Wg, tN_bg, tN_Wout, tN_bout,
        tP_bin, tP_Wf, tP_bf, tP_Wg, tP_bg, tP_Wout, tP_bout,
        unb, hpr);
  } else {
    k_tcn  <<<dim3(20, 334), dim3(256), 0, stream>>>(x, fcx_W, fcx_b, temb, node_list, off,
        tN_Win, tN_bin, tN_Wf, tN_bf, tN_Wg, tN_bg, tN_Wout, tN_bout,
        tP_Win, tP_bin, tP_Wf, tP_bf, tP_Wg, tP_bg, tP_Wout, tP_bout,
        unb, hpr);
  }
  k_bnstats<<<dim3(128), dim3(256), 0, stream>>>(unb, hpr, stats);
  k_bnapply<<<dim3(1000),dim3(256), 0, stream>>>(unb, hpr, stats, bn1_g, bn1_b, bnP_g, bnP_b);
  k_tmp1<<<dim3(256), dim3(256), 0, stream>>>(ind, nv_p1, nv_pk, tmp1);

  dim3 ag(32, 16);
  const float* nil = nullptr;
  // gcn1: geo adjacency on h_prev
  k_attn<0,0,0,0><<<ag, 256, 0, stream>>>(geo, nil,nil,nil, nil,nil,
                                 hpr, nil,nil, nil,nil, nullptr, zt1);
  k_attn<0,0,1,0><<<ag, 256, 0, stream>>>(geo, nil,nil,nil, nil,nil,
                                 zt1, hpr, zt1, gcn1_W, gcn1_b, cur, nullptr);
  // gcn2: causal adjacency on unbias
  if (useP){
    k_attn_p1<1,0><<<ag, 256, 0, stream>>>(unb, nil, core_f, hpr, nil, unb, Pb, zt1);
    k_attn_p2<1>  <<<ag, 256, 0, stream>>>(Pb, zt1, unb, gcn2_W, gcn2_b, cur);
  } else {
    k_attn<1,0,0,0><<<ag, 256, 0, stream>>>(nil, unb,nil, core_f, hpr,nil,
                                   unb, nil,nil, nil,nil, nullptr, zt1);
    k_attn<1,0,1,1><<<ag, 256, 0, stream>>>(nil, unb,nil, core_f, hpr,nil,
                                   zt1, unb, zt1, gcn2_W, gcn2_b, cur, nullptr);
  }
  // gcnp: adaptive adjacency on unbias
  if (useP){
    k_attn_p1<2,1><<<ag, 256, 0, stream>>>(nil, nv_p2, tmp1, nil, nv_p3, unb, Pb, zt1);
    k_attn_p2<1>  <<<ag, 256, 0, stream>>>(Pb, zt1, unb, gcnp_W, gcnp_b, cur);
  } else {
    k_attn<2,1,0,0><<<ag, 256, 0, stream>>>(nil, nil,nv_p2, tmp1, nil,nv_p3,
                                   unb, nil,nil, nil,nil, nullptr, zt1);
    k_attn<2,1,1,1><<<ag, 256, 0, stream>>>(nil, nil,nv_p2, tmp1, nil,nv_p3,
                                   zt1, unb, zt1, gcnp_W, gcnp_b, cur, nullptr);
  }
  // head
  k_out<<<dim3(1000), dim3(128), 0, stream>>>(cur, out_W1, out_b1, out_W2, out_b2, (float*)d_out);
}